// Round 9
// baseline (475.496 us; speedup 1.0000x reference)
//
#include <hip/hip_runtime.h>

#define DM 1024
#define NH 16
#define DH 64
#define QL 1024
#define KL 2048

typedef short s16x8 __attribute__((ext_vector_type(8)));
typedef float f32x4 __attribute__((ext_vector_type(4)));
typedef unsigned int u32x4 __attribute__((ext_vector_type(4)));

__device__ __forceinline__ unsigned short f2bf(float f) {
  unsigned int u = __builtin_bit_cast(unsigned int, f);
  u += 0x7fffu + ((u >> 16) & 1u);
  return (unsigned short)(u >> 16);
}
__device__ __forceinline__ float bf2f(unsigned short b) {
  unsigned int u = ((unsigned int)b) << 16;
  return __builtin_bit_cast(float, u);
}
__device__ __forceinline__ f32x4 mfma16(s16x8 a, s16x8 b, f32x4 c) {
  return __builtin_amdgcn_mfma_f32_16x16x32_bf16(a, b, c, 0, 0, 0);
}
// async global->LDS, 16B per lane; LDS dest = wave-uniform base + lane*16
__device__ __forceinline__ void gl2lds16(const void* g, void* l) {
  __builtin_amdgcn_global_load_lds(
      (const __attribute__((address_space(1))) unsigned int*)g,
      (__attribute__((address_space(3))) unsigned int*)l, 16, 0, 0);
}

// Fragment-packed layouts (all bf16):
//  qP/qrP: [bh][qt=row/16][f=dim/32][lane=((dim>>3)&3)*16+(row&15)][j=dim&7]   (A-frag)
//  kP:     [bh][kt=key/16][f][lane][j]  (B-frag; lane=((dim>>3)&3)*16+(key&15))
//  rP:     [h][xt=row/16][f][lane][j]   (B-frag)
//  vP:     [bh][kt=key/32][nt=dim/16][lane=((key>>2)&3)*16+(dim&15)][e=(key&3)+4*((key>>4)&1)]
//          (A-frag of PV with keys PERMUTED inside each 32-tile by kappa(quad,e)=4q+(e&3)+16(e>>2),
//           so swapped-QK's lane-local P feeds PV's B operand with NO cross-lane movement.)

// ---------------- fused prep: blocks 0..6143 input conversion, 6144..7423 weights ------
__global__ __launch_bounds__(256) void prep_all(
    const float* __restrict__ h, const float* __restrict__ mem, const float* __restrict__ r,
    const float* __restrict__ Wq, const float* __restrict__ Wk, const float* __restrict__ Wv,
    const float* __restrict__ Wr, const float* __restrict__ Wo,
    unsigned short* __restrict__ catb, unsigned short* __restrict__ rb,
    unsigned short* __restrict__ wqt, unsigned short* __restrict__ wkvt,
    unsigned short* __restrict__ wrt,
    unsigned short* __restrict__ wohi, unsigned short* __restrict__ wolo)
{
  __shared__ unsigned short tH[64][72];
  __shared__ unsigned short tL[64][72];
  if (blockIdx.x < 6144) {
    int idx = blockIdx.x * 256 + threadIdx.x;           // 0 .. 1.5M-1
    if (idx < 1048576) {                                // catb: 4M u16, 4 per thread
      int e = idx * 4;
      int row = e >> 10, col = e & 1023;
      int b = row >> 11, t = row & 2047;
      const float* s = (t < 1024) ? &mem[((size_t)(b * 1024 + t)) * 1024 + col]
                                  : &h[((size_t)(b * 1024 + t - 1024)) * 1024 + col];
      float4 v = *(const float4*)s;
      *(ushort4*)&catb[e] = make_ushort4(f2bf(v.x), f2bf(v.y), f2bf(v.z), f2bf(v.w));
    } else {
      int e = (idx - 1048576) * 4;                      // rb: 2M elements
      float4 v = *(const float4*)&r[e];
      *(ushort4*)&rb[e] = make_ushort4(f2bf(v.x), f2bf(v.y), f2bf(v.z), f2bf(v.w));
    }
    return;
  }
  int q = blockIdx.x - 6144;
  int job = q >> 8;
  int tb = q & 255;
  int sr0 = (tb >> 4) * 64, sc0 = (tb & 15) * 64;
  const float* src = (job == 0) ? Wq : (job == 1) ? Wk : (job == 2) ? Wv : (job == 3) ? Wr : Wo;
  int tid = threadIdx.x;
  int rr = tid >> 4, c4 = (tid & 15) * 4;
#pragma unroll
  for (int i = 0; i < 4; ++i) {
    int row = rr + i * 16;
    float4 v = *(const float4*)&src[(size_t)(sr0 + row) * 1024 + sc0 + c4];
    float vv[4] = {v.x, v.y, v.z, v.w};
#pragma unroll
    for (int j = 0; j < 4; ++j) {
      unsigned short hi = f2bf(vv[j]);
      tH[c4 + j][row] = hi;
      if (job == 4) tL[c4 + j][row] = f2bf(vv[j] - bf2f(hi));
    }
  }
  __syncthreads();
  unsigned short* dst = (job == 0) ? wqt : (job == 1) ? wkvt
                      : (job == 2) ? (wkvt + (size_t)1024 * 1024)
                      : (job == 3) ? wrt : wohi;
#pragma unroll
  for (int i = 0; i < 4; ++i) {
    int row = rr + i * 16;
    size_t o = (size_t)(sc0 + row) * 1024 + sr0 + c4;
    *(ushort4*)&dst[o] = make_ushort4(tH[row][c4], tH[row][c4 + 1], tH[row][c4 + 2], tH[row][c4 + 3]);
    if (job == 4)
      *(ushort4*)&wolo[o] = make_ushort4(tL[row][c4], tL[row][c4 + 1], tL[row][c4 + 2], tL[row][c4 + 3]);
  }
}

// ---------------- projection GEMMs (bf16 MFMA, 128x128 tile, BK=32, double-buffered) --
__global__ __launch_bounds__(256) void gemm_all(
    const unsigned short* __restrict__ catb, const unsigned short* __restrict__ rb,
    const unsigned short* __restrict__ wqt, const unsigned short* __restrict__ wkvt,
    const unsigned short* __restrict__ wrt,
    const float* __restrict__ rwb, const float* __restrict__ rrb,
    unsigned short* __restrict__ qwP, unsigned short* __restrict__ qrP,
    unsigned short* __restrict__ kP, unsigned short* __restrict__ vP,
    unsigned short* __restrict__ rP)
{
  __shared__ __align__(16) unsigned short As[2][128 * 32];
  __shared__ __align__(16) unsigned short Bs[2][128 * 32];
  int blk = blockIdx.x, tid = threadIdx.x;
  int job, mb, nb;
  const unsigned short *A, *Bt;
  if (blk < 128)      { job = 0; A = catb; Bt = wqt;  mb = blk >> 3; nb = blk & 7; }
  else if (blk < 640) { job = 1; A = catb; Bt = wkvt; int q = blk - 128; mb = q >> 4; nb = q & 15; }
  else                { job = 2; A = rb;   Bt = wrt;  int q = blk - 640; mb = q >> 3; nb = q & 7; }

  const int w = tid >> 6;
  const int r0 = tid >> 2;                 // chunk0 row (0..63)
  const int c0u = (tid & 3) * 8;           // u16 col offset within 32-wide slab
  int ga_r0 = mb * 128 + r0, ga_r1 = mb * 128 + 64 + r0;
  if (job == 0) {
    ga_r0 = ((ga_r0 >> 10) << 11) + 1024 + (ga_r0 & 1023);
    ga_r1 = ((ga_r1 >> 10) << 11) + 1024 + (ga_r1 & 1023);
  }
  const unsigned short* gA0 = A + (size_t)ga_r0 * 1024 + c0u;
  const unsigned short* gA1 = A + (size_t)ga_r1 * 1024 + c0u;
  const unsigned short* gB0 = Bt + (size_t)(nb * 128 + r0) * 1024 + c0u;
  const unsigned short* gB1 = Bt + (size_t)(nb * 128 + 64 + r0) * 1024 + c0u;

  const int lane = tid & 63;
  const int lc = lane & 15, quad = lane >> 4;
  const int wm = (w & 1) * 64, wn = (w >> 1) * 64;

  auto stage = [&](int k0, int bi) {
    gl2lds16(gA0 + k0, (char*)As[bi] + w * 1024);
    gl2lds16(gA1 + k0, (char*)As[bi] + 4096 + w * 1024);
    gl2lds16(gB0 + k0, (char*)Bs[bi] + w * 1024);
    gl2lds16(gB1 + k0, (char*)Bs[bi] + 4096 + w * 1024);
  };

  f32x4 acc[4][4];
#pragma unroll
  for (int mt = 0; mt < 4; ++mt)
#pragma unroll
    for (int nt = 0; nt < 4; ++nt) { acc[mt][nt][0] = 0.f; acc[mt][nt][1] = 0.f; acc[mt][nt][2] = 0.f; acc[mt][nt][3] = 0.f; }

  stage(0, 0);
  __syncthreads();
  for (int k0 = 0; k0 < 1024; k0 += 32) {
    int cur = (k0 >> 5) & 1;
    if (k0 + 32 < 1024) stage(k0 + 32, cur ^ 1);
    s16x8 af[4], bfr[4];
#pragma unroll
    for (int mt = 0; mt < 4; ++mt) af[mt] = *(const s16x8*)&As[cur][(wm + mt * 16 + lc) * 32 + quad * 8];
#pragma unroll
    for (int nt = 0; nt < 4; ++nt) bfr[nt] = *(const s16x8*)&Bs[cur][(wn + nt * 16 + lc) * 32 + quad * 8];
#pragma unroll
    for (int mt = 0; mt < 4; ++mt)
#pragma unroll
      for (int nt = 0; nt < 4; ++nt) acc[mt][nt] = mfma16(af[mt], bfr[nt], acc[mt][nt]);
    __syncthreads();
  }

#pragma unroll
  for (int mt = 0; mt < 4; ++mt) {
    int t4 = mb * 128 + wm + mt * 16 + quad * 4;
#pragma unroll
    for (int nt = 0; nt < 4; ++nt) {
      int n = nb * 128 + wn + nt * 16 + lc;
      if (job == 0) {
        int hh = n >> 6, dh = n & 63;
        int f = dh >> 5, qd = (dh >> 3) & 3, j = dh & 7;
        float bw = rwb[n], br = rrb[n];
        int bb = t4 >> 10, trow = t4 & 1023;
        size_t tbb = ((((size_t)(bb * NH + hh) * 64 + (trow >> 4)) * 2 + f) * 512) + qd * 128 + j;
        int l0 = trow & 15;
#pragma unroll
        for (int rr = 0; rr < 4; ++rr) {
          qwP[tbb + (l0 + rr) * 8] = f2bf(acc[mt][nt][rr] + bw);
          qrP[tbb + (l0 + rr) * 8] = f2bf(acc[mt][nt][rr] + br);
        }
      } else if (job == 1) {
        int bb = t4 >> 11, t = t4 & 2047;
        if (n < 1024) {
          int hh = n >> 6, dh = n & 63;
          int f = dh >> 5, qd = (dh >> 3) & 3, j = dh & 7;
          size_t tbb = ((((size_t)(bb * NH + hh) * 128 + (t >> 4)) * 2 + f) * 512) + qd * 128 + j;
          int l0 = t & 15;
#pragma unroll
          for (int rr = 0; rr < 4; ++rr)
            kP[tbb + (l0 + rr) * 8] = f2bf(acc[mt][nt][rr]);
        } else {
          int n2 = n - 1024, hh = n2 >> 6, dh = n2 & 63;
          int bhv = bb * NH + hh;
          int kt = t >> 5;
          int ntv = dh >> 4;
          // key-permuted V A-frag: key tau=t&31 sits at lane-quad (tau>>2)&3, elem (tau&3)+4*((tau>>4)&1)
          int lanev = (((t >> 2) & 3) << 4) + (dh & 15);
          int elemv = ((t >> 4) & 1) << 2;          // t4 is a multiple of 4: elems elemv..elemv+3
          ushort4 pk = make_ushort4(f2bf(acc[mt][nt][0]), f2bf(acc[mt][nt][1]),
                                    f2bf(acc[mt][nt][2]), f2bf(acc[mt][nt][3]));
          *(ushort4*)&vP[(((size_t)bhv * 64 + kt) * 4 + ntv) * 512 + lanev * 8 + elemv] = pk;
        }
      } else {
        int hh = n >> 6, dh = n & 63;
        int f = dh >> 5, qd = (dh >> 3) & 3, j = dh & 7;
        size_t tbb = (((size_t)hh * 128 + (t4 >> 4)) * 2 + f) * 512 + qd * 128 + j;
        int l0 = t4 & 15;
#pragma unroll
        for (int rr = 0; rr < 4; ++rr)
          rP[tbb + (l0 + rr) * 8] = f2bf(acc[mt][nt][rr]);
      }
    }
  }
}

// ---------------- fused flash attention with rel-shift (bf16 MFMA) --------------------
// TWO-HALF K processing to halve LDS (66 KB -> 34 KB) and DOUBLE occupancy (2 -> 4
// blocks/CU, 32 waves = 100% of slots). Each half H covers keys [1024H, 1024H+1024):
//   phase0(H) computes only the raw-BD column windows that half needs (~66 of 128 tiles;
//   half0 = direct stores only, half1 = wrap stores + 17th row + diagonal hole), then the
//   main split-K loop runs 4 chunks/wave over that half. bdS cols = key - 1024H.
// Main loop: swapped QK^T (mfma(K,Q)), BD folded into C operand, P lane-local via
// v_cvt_pk_bf16_f32 into key-permuted V tiles, macro unroll-2 with named A/B reg sets.
// XCD-swizzled grid.
#define BDSTR 1060          // u16 row stride: 530 words = 18 mod 32 -> conflict-free-ish b64 reads
#define OSTR 65             // f32 merge-row stride
__global__ __launch_bounds__(512, 8) void attn(
    const unsigned short* __restrict__ qwP, const unsigned short* __restrict__ qrP,
    const unsigned short* __restrict__ kP, const unsigned short* __restrict__ vP,
    const unsigned short* __restrict__ rP,
    unsigned short* __restrict__ avhi, unsigned short* __restrict__ avlo)
{
  __shared__ __align__(16) unsigned short bdS[16 * BDSTR];   // 33920 B
  float* oS = (float*)bdS;                 // merge overlay: [8][16][OSTR] f32 = 33280 B
  float* lS = (float*)bdS + 8 * 16 * OSTR; // [8][16] f32 (33280..33792 B, fits 33920)

  const int tid = threadIdx.x;
  const int w = tid >> 6, lane = tid & 63;
  const int lc = lane & 15, quad = lane >> 4;
  // XCD swizzle: hw block -> semantic block so one (b,h)'s 64 q-tiles share an XCD L2
  const int sem = (blockIdx.x & 7) * 256 + (blockIdx.x >> 3);
  const int is = sem & 63, h = (sem >> 6) & 15, b = sem >> 10;
  const int i0 = is * 16;
  const size_t bh = (size_t)b * NH + h;

  const unsigned short* qwP_p = qwP + bh * 65536;
  const unsigned short* qrP_p = qrP + bh * 65536;
  const unsigned short* kP_p  = kP + bh * 131072;
  const unsigned short* vP_p  = vP + bh * (size_t)KL * DH + lane * 8;
  const unsigned short* rP_p  = rP + (size_t)h * 131072;

  // Q fragments (hoisted; used across both halves)
  s16x8 qwf0 = *(const s16x8*)(qwP_p + is * 1024 + lane * 8);
  s16x8 qwf1 = *(const s16x8*)(qwP_p + is * 1024 + 512 + lane * 8);
  s16x8 qa00 = *(const s16x8*)(qrP_p + is * 1024 + lane * 8);
  s16x8 qa01 = *(const s16x8*)(qrP_p + is * 1024 + 512 + lane * 8);

  f32x4 O[4];
#pragma unroll
  for (int nt = 0; nt < 4; ++nt) { O[nt][0] = 0.f; O[nt][1] = 0.f; O[nt][2] = 0.f; O[nt][3] = 0.f; }
  float lsumQ = 0.f;

  const unsigned short* bdlane = bdS + lc * BDSTR + quad * 4;   // q-row = lc, keys 4*quad+..
  const int rbq = quad * 4 * BDSTR;        // per-lane phase-0 row base (u16 units)
  const int cmax = 1006 - i0;              // raw row i0+16 only needed at cols <= cmax
  const float E2S = 0.18033688011112042f;  // 0.125 * log2(e)
  const float E2B = -17.312340490667562f;  // -12  * log2(e)

  // A/B named register sets; straight-line macros (no lambdas / pointer params).
  s16x8 ka0A, ka1A, kb0A, kb1A, v0A, v1A, v2A, v3A;
  s16x8 ka0B, ka1B, kb0B, kb1B, v0B, v1B, v2B, v3B;
  uint2 bq0A, bq1A, bq0B, bq1B;

#define LOADC(S, kg, kc) { \
    const unsigned short* kp_ = kP_p + (size_t)((kg) >> 4) * 1024 + lane * 8; \
    ka0##S = *(const s16x8*)kp_; \
    ka1##S = *(const s16x8*)(kp_ + 512); \
    kb0##S = *(const s16x8*)(kp_ + 1024); \
    kb1##S = *(const s16x8*)(kp_ + 1536); \
    const unsigned short* bp_ = vP_p + (size_t)((kg) >> 5) * 2048; \
    v0##S = *(const s16x8*)bp_; \
    v1##S = *(const s16x8*)(bp_ + 512); \
    v2##S = *(const s16x8*)(bp_ + 1024); \
    v3##S = *(const s16x8*)(bp_ + 1536); \
    bq0##S = *(const uint2*)(bdlane + (kc)); \
    bq1##S = *(const uint2*)(bdlane + (kc) + 16); \
  }

#define COMPUTE(S) { \
    f32x4 c_; \
    c_[0] = __builtin_bit_cast(float, bq0##S.x << 16); \
    c_[1] = __builtin_bit_cast(float, bq0##S.x & 0xFFFF0000u); \
    c_[2] = __builtin_bit_cast(float, bq0##S.y << 16); \
    c_[3] = __builtin_bit_cast(float, bq0##S.y & 0xFFFF0000u); \
    c_ = mfma16(ka0##S, qwf0, c_); \
    c_ = mfma16(ka1##S, qwf1, c_); \
    f32x4 d_; \
    d_[0] = __builtin_bit_cast(float, bq1##S.x << 16); \
    d_[1] = __builtin_bit_cast(float, bq1##S.x & 0xFFFF0000u); \
    d_[2] = __builtin_bit_cast(float, bq1##S.y << 16); \
    d_[3] = __builtin_bit_cast(float, bq1##S.y & 0xFFFF0000u); \
    d_ = mfma16(kb0##S, qwf0, d_); \
    d_ = mfma16(kb1##S, qwf1, d_); \
    float p0_[4], p1_[4]; \
    _Pragma("unroll") \
    for (int rr_ = 0; rr_ < 4; ++rr_) { \
      p0_[rr_] = __builtin_amdgcn_exp2f(fmaf(c_[rr_], E2S, E2B)); \
      p1_[rr_] = __builtin_amdgcn_exp2f(fmaf(d_[rr_], E2S, E2B)); \
    } \
    lsumQ += ((p0_[0] + p0_[1]) + (p0_[2] + p0_[3])) + ((p1_[0] + p1_[1]) + (p1_[2] + p1_[3])); \
    unsigned int w0_, w1_, w2_, w3_; \
    asm("v_cvt_pk_bf16_f32 %0, %1, %2" : "=v"(w0_) : "v"(p0_[0]), "v"(p0_[1])); \
    asm("v_cvt_pk_bf16_f32 %0, %1, %2" : "=v"(w1_) : "v"(p0_[2]), "v"(p0_[3])); \
    asm("v_cvt_pk_bf16_f32 %0, %1, %2" : "=v"(w2_) : "v"(p1_[0]), "v"(p1_[1])); \
    asm("v_cvt_pk_bf16_f32 %0, %1, %2" : "=v"(w3_) : "v"(p1_[2]), "v"(p1_[3])); \
    u32x4 pw4_ = {w0_, w1_, w2_, w3_}; \
    s16x8 pf_ = __builtin_bit_cast(s16x8, pw4_); \
    O[0] = mfma16(v0##S, pf_, O[0]); \
    O[1] = mfma16(v1##S, pf_, O[1]); \
    O[2] = mfma16(v2##S, pf_, O[2]); \
    O[3] = mfma16(v3##S, pf_, O[3]); \
  }

#pragma unroll 1
  for (int H = 0; H < 2; ++H) {
    if (H) __syncthreads();                 // all half-0 bdS readers done before overwrite

    // ---- phase 0 (half H): raw BD tiles this half needs, pre-shifted stores ----
    if (H && tid < 16) {                    // diagonal hole (key = q+1025) lives in half 1
      int kz = i0 + tid + 1025;
      if (kz < 2048) bdS[tid * BDSTR + (kz - 1024)] = 0;
    }
    {
      int n, xA_hi = 0, xB_lo = 0, xbase = 0;
      if (H == 0) {
        xbase = (1008 - i0) >> 4;
        n = ((2046 - i0) >> 4) - xbase + 1;           // <= 66
      } else {
        xA_hi = (1022 - i0) >> 4;                     // wrap window [0, xA_hi]
        xB_lo = (2032 - i0) >> 4;                     // direct window [xB_lo, 127]
        n = (xA_hi + 1) + (128 - xB_lo);              // <= 66
      }
      s16x8 qa10, qa11;
      if (H) {                                        // 17th-row fragments (half 1 only)
        int r1 = i0 + 16 + lc; if (r1 > 1023) r1 = 1023;
        int off1 = (r1 >> 4) * 1024 + (quad * 16 + (r1 & 15)) * 8;
        qa10 = *(const s16x8*)(qrP_p + off1);
        qa11 = *(const s16x8*)(qrP_p + off1 + 512);
      }
#pragma unroll 1
      for (int j = 0; j < 9; ++j) {
        int t = w + 8 * j;                            // wave-uniform
        if (t >= n) break;
        int xt = (H == 0) ? (xbase + t)
                          : ((t <= xA_hi) ? t : (xB_lo + (t - xA_hi - 1)));
        const unsigned short* rp = rP_p + xt * 1024 + lane * 8;
        s16x8 cf0 = *(const s16x8*)rp;
        s16x8 cf1 = *(const s16x8*)(rp + 512);
        f32x4 c0; c0[0] = 0.f; c0[1] = 0.f; c0[2] = 0.f; c0[3] = 0.f;
        c0 = mfma16(qa00, cf0, c0); c0 = mfma16(qa01, cf1, c0);
        int c = xt * 16 + lc;
        if (H == 0) {
#pragma unroll
          for (int rr = 0; rr < 4; ++rr) {
            int row = quad * 4 + rr;
            int s = c + i0 + row - 1023;              // direct key; this half keeps [0,1024)
            if ((unsigned)s < 1024u)
              bdS[rbq + rr * BDSTR + s] = f2bf(c0[rr]);
          }
        } else {
#pragma unroll
          for (int rr = 0; rr < 4; ++rr) {
            int s = c + i0 + quad * 4 + rr - 1023;
            // s>=1024: direct store at col s-1024; s<0: wrap to row-1 at col s+1024
            // (row-1)*BDSTR + (s+1024) == row*BDSTR + s - 36   [BDSTR=1060]
            int off = (s >= 1024) ? (s - 1024) : (s - 36);
            if (s >= 1024 || (s < 0 && (quad | rr) != 0))
              bdS[rbq + rr * BDSTR + off] = f2bf(c0[rr]);
          }
          if (xt * 16 <= cmax) {                      // 17th row -> row 15 wrap keys
            f32x4 c1; c1[0] = 0.f; c1[1] = 0.f; c1[2] = 0.f; c1[3] = 0.f;
            c1 = mfma16(qa10, cf0, c1); c1 = mfma16(qa11, cf1, c1);
            if (lane < 16) {
              int key2 = c + i0 + 1041;               // always >= 1041 (half 1)
              if (key2 < 2048) bdS[15 * BDSTR + (key2 - 1024)] = f2bf(c1[0]);
            }
          }
        }
      }
    }
    __syncthreads();

    // ---- main split-K (this half): wave w handles keys [1024H + w*128, +128), 4 chunks ----
    const int kg0 = H * 1024 + w * 128;               // global key base (kP/vP)
    const int kc0 = w * 128;                          // bdS column base
    LOADC(A, kg0, kc0)
#pragma unroll 1
    for (int s2 = 0; s2 < 4; s2 += 2) {
      LOADC(B, kg0 + (s2 + 1) * 32, kc0 + (s2 + 1) * 32)
      COMPUTE(A)
      if (s2 < 2) LOADC(A, kg0 + (s2 + 2) * 32, kc0 + (s2 + 2) * 32)
      COMPUTE(B)
    }
  }
#undef LOADC
#undef COMPUTE

  // row-sum over quads (q = lc is lane-local)
  lsumQ += __shfl_xor(lsumQ, 16);
  lsumQ += __shfl_xor(lsumQ, 32);

  // ---- merge: plain sums over 8 waves ----
  __syncthreads();               // all waves done with bdS reads
#pragma unroll
  for (int nt = 0; nt < 4; ++nt)
#pragma unroll
    for (int rr = 0; rr < 4; ++rr)
      oS[(w * 16 + lc) * OSTR + nt * 16 + quad * 4 + rr] = O[nt][rr];
  if (lane < 16) lS[w * 16 + lc] = lsumQ;
  __syncthreads();

  if (tid < 256) {
    int r = tid >> 4, c0 = (tid & 15) * 4;
    float L = 0.f, a0 = 0.f, a1 = 0.f, a2 = 0.f, a3 = 0.f;
#pragma unroll
    for (int wv = 0; wv < 8; ++wv) {
      L += lS[wv * 16 + r];
      const float* op = oS + (wv * 16 + r) * OSTR + c0;
      a0 += op[0]; a1 += op[1]; a2 += op[2]; a3 += op[3];
    }
    float inv = 1.0f / L;
    float v[4] = {a0 * inv, a1 * inv, a2 * inv, a3 * inv};
    unsigned short hi[4], lo[4];
#pragma unroll
    for (int j = 0; j < 4; ++j) {
      hi[j] = f2bf(v[j]);
      lo[j] = f2bf(v[j] - bf2f(hi[j]));
    }
    size_t oidx = ((size_t)(b * QL + i0 + r)) * DM + h * DH + c0;
    *(ushort4*)&avhi[oidx] = make_ushort4(hi[0], hi[1], hi[2], hi[3]);
    *(ushort4*)&avlo[oidx] = make_ushort4(lo[0], lo[1], lo[2], lo[3]);
  }
}

// ---------------- final GEMM: out = av @ Wo, fused 3-segment split-bf16 ----------------
// XCD-swizzled (512 = 8 x 64, bijective): each XCD owns 4 contiguous mb rows -> avhi/avlo
// panels stay L2-local; Wo panels (4 MB total) fit L2 regardless.
__global__ __launch_bounds__(256) void gemm_final(
    const unsigned short* __restrict__ avhi, const unsigned short* __restrict__ avlo,
    const unsigned short* __restrict__ wohi, const unsigned short* __restrict__ wolo,
    float* __restrict__ out)
{
  __shared__ __align__(16) unsigned short S[2][4][64 * 32];   // [buf][op][64][32]
  int tid = threadIdx.x;
  int sem = (blockIdx.x & 7) * 64 + (blockIdx.x >> 3);   // XCD swizzle
  int mb = sem >> 4, nb = sem & 15;    // 32 x 16

  const int w = tid >> 6, lane = tid & 63;
  const int srow = w * 16 + (lane >> 2);
  const int scu = (lane & 3) * 8;
  const size_t arow = (size_t)(mb * 64 + srow) * 1024 + scu;
  const size_t brow = (size_t)(nb * 64 + srow) * 1024 + scu;

  const int lc = lane & 15, quad = lane >> 4;
  const int wm = (w & 1) * 32, wn = (w >> 1) * 32;

  auto stage = [&](int k0, int bi) {
    gl2lds16(avhi + arow + k0, (char*)S[bi][0] + w * 1024);
    gl2lds16(avlo + arow + k0, (char*)S[bi][1] + w * 1024);
    gl2lds16(wohi + brow + k0, (char*)S[bi][2] + w * 1024);
    gl2lds16(wolo + brow + k0, (char*)S[bi][3] + w * 1024);
  };

  f32x4 acc[2][2];
#pragma unroll
  for (int mt = 0; mt < 2; ++mt)
#pragma unroll
    for (int nt = 0; nt < 2; ++nt) { acc[mt][nt][0] = 0.f; acc[mt][nt][1] = 0.f; acc[mt][nt][2] = 0.f; acc[mt][nt][3] = 0.f; }

  stage(0, 0);
  __syncthreads();
  for (int k0 = 0; k0 < 1024; k0 += 32) {
    int cur = (k0 >> 5) & 1;
    if (k0 + 32 < 1024) stage(k0 + 32, cur ^ 1);
    s16x8 ah[2], al[2], bh[2], bl[2];
#pragma unroll
    for (int mt = 0; mt < 2; ++mt) {
      int off = (wm + mt * 16 + lc) * 32 + quad * 8;
      ah[mt] = *(const s16x8*)&S[cur][0][off];
      al[mt] = *(const s16x8*)&S[cur][1][off];
    }
#pragma unroll
    for (int nt = 0; nt < 2; ++nt) {
      int off = (wn + nt * 16 + lc) * 32 + quad * 8;
      bh[nt] = *(const s16x8*)&S[cur][2][off];
      bl[nt] = *(const s16x8*)&S[cur][3][off];
    }
#pragma unroll
    for (int mt = 0; mt < 2; ++mt)
#pragma unroll
      for (int nt = 0; nt < 2; ++nt) {
        acc[mt][nt] = mfma16(ah[mt], bh[nt], acc[mt][nt]);
        acc[mt][nt] = mfma16(ah[mt], bl[nt], acc[mt][nt]);
        acc[mt][nt] = mfma16(al[mt], bh[nt], acc[mt][nt]);
      }
    __syncthreads();
  }

#pragma unroll
  for (int mt = 0; mt < 2; ++mt)
#pragma unroll
    for (int nt = 0; nt < 2; ++nt) {
      int n = nb * 64 + wn + nt * 16 + lc;
#pragma unroll
      for (int rr = 0; rr < 4; ++rr) {
        int m = mb * 64 + wm + mt * 16 + quad * 4 + rr;
        out[(size_t)m * 1024 + n] = acc[mt][nt][rr];
      }
    }
}

extern "C" void kernel_launch(void* const* d_in, const int* in_sizes, int n_in,
                              void* d_out, int out_size, void* d_ws, size_t ws_size,
                              hipStream_t stream) {
  (void)in_sizes; (void)n_in; (void)out_size; (void)ws_size;
  const float* h   = (const float*)d_in[0];
  const float* mem = (const float*)d_in[1];
  const float* r   = (const float*)d_in[2];
  const float* Wq  = (const float*)d_in[3];
  const float* Wk  = (const float*)d_in[4];
  const float* Wv  = (const float*)d_in[5];
  const float* Wr  = (const float*)d_in[6];
  const float* Wo  = (const float*)d_in[7];
  const float* rwb = (const float*)d_in[8];
  const float* rrb = (const float*)d_in[9];
  float* out = (float*)d_out;

  char* ws = (char*)d_ws;
  unsigned short* catb = (unsigned short*)(ws + 0);          // 8 MB
  unsigned short* rb   = (unsigned short*)(ws + 8388608);    // 4 MB
  unsigned short* wqt  = (unsigned short*)(ws + 12582912);   // 2 MB
  unsigned short* wkvt = (unsigned short*)(ws + 14680064);   // 4 MB
  unsigned short* wrt  = (unsigned short*)(ws + 18874368);   // 2 MB
  unsigned short* wohi = (unsigned short*)(ws + 20971520);   // 2 MB
  unsigned short* wolo = (unsigned short*)(ws + 23068672);   // 2 MB
  unsigned short* qwP  = (unsigned short*)(ws + 25165824);   // 4 MB (A-frag packed)
  unsigned short* qrP  = (unsigned short*)(ws + 29360128);   // 4 MB (A-frag packed)
  unsigned short* kPb  = (unsigned short*)(ws + 33554432);   // 8 MB (B-frag packed)
  unsigned short* vPb  = (unsigned short*)(ws + 41943040);   // 8 MB (key-permuted A-frag)
  unsigned short* rPb  = (unsigned short*)(ws + 50331648);   // 4 MB (B-frag packed)
  unsigned short* avhi = (unsigned short*)(ws + 54525952);   // 4 MB
  unsigned short* avlo = (unsigned short*)(ws + 58720256);   // 4 MB

  prep_all<<<7424, 256, 0, stream>>>(h, mem, r, Wq, Wk, Wv, Wr, Wo,
                                     catb, rb, wqt, wkvt, wrt, wohi, wolo);
  gemm_all<<<768, 256, 0, stream>>>(catb, rb, wqt, wkvt, wrt, rwb, rrb,
                                    qwP, qrP, kPb, vPb, rPb);
  attn<<<2048, 512, 0, stream>>>(qwP, qrP, kPb, vPb, rPb, avhi, avlo);
  gemm_final<<<512, 256, 0, stream>>>(avhi, avlo, wohi, wolo, out);
}

// Round 10
// 416.659 us; speedup vs baseline: 1.1412x; 1.1412x over previous
//
#include <hip/hip_runtime.h>

#define DM 1024
#define NH 16
#define DH 64
#define QL 1024
#define KL 2048

typedef short s16x8 __attribute__((ext_vector_type(8)));
typedef float f32x4 __attribute__((ext_vector_type(4)));
typedef unsigned int u32x4 __attribute__((ext_vector_type(4)));

__device__ __forceinline__ unsigned short f2bf(float f) {
  unsigned int u = __builtin_bit_cast(unsigned int, f);
  u += 0x7fffu + ((u >> 16) & 1u);
  return (unsigned short)(u >> 16);
}
__device__ __forceinline__ float bf2f(unsigned short b) {
  unsigned int u = ((unsigned int)b) << 16;
  return __builtin_bit_cast(float, u);
}
__device__ __forceinline__ f32x4 mfma16(s16x8 a, s16x8 b, f32x4 c) {
  return __builtin_amdgcn_mfma_f32_16x16x32_bf16(a, b, c, 0, 0, 0);
}
// async global->LDS, 16B per lane; LDS dest = wave-uniform base + lane*16
__device__ __forceinline__ void gl2lds16(const void* g, void* l) {
  __builtin_amdgcn_global_load_lds(
      (const __attribute__((address_space(1))) unsigned int*)g,
      (__attribute__((address_space(3))) unsigned int*)l, 16, 0, 0);
}

// Fragment-packed layouts (all bf16):
//  qP/qrP: [bh][qt=row/16][f=dim/32][lane=((dim>>3)&3)*16+(row&15)][j=dim&7]   (A-frag)
//  kP:     [bh][kt=key/16][f][lane][j]  (B-frag; lane=((dim>>3)&3)*16+(key&15))
//  rP:     [h][xt=row/16][f][lane][j]   (B-frag)
//  vP:     [bh][kt=key/32][nt=dim/16][lane=((key>>2)&3)*16+(dim&15)][e=(key&3)+4*((key>>4)&1)]
//          (A-frag of PV with keys PERMUTED inside each 32-tile by kappa(quad,e)=4q+(e&3)+16(e>>2),
//           so swapped-QK's lane-local P feeds PV's B operand with NO cross-lane movement.)

// ---------------- fused prep: blocks 0..6143 input conversion, 6144..7423 weights ------
__global__ __launch_bounds__(256) void prep_all(
    const float* __restrict__ h, const float* __restrict__ mem, const float* __restrict__ r,
    const float* __restrict__ Wq, const float* __restrict__ Wk, const float* __restrict__ Wv,
    const float* __restrict__ Wr, const float* __restrict__ Wo,
    unsigned short* __restrict__ catb, unsigned short* __restrict__ rb,
    unsigned short* __restrict__ wqt, unsigned short* __restrict__ wkvt,
    unsigned short* __restrict__ wrt,
    unsigned short* __restrict__ wohi, unsigned short* __restrict__ wolo)
{
  __shared__ unsigned short tH[64][72];
  __shared__ unsigned short tL[64][72];
  if (blockIdx.x < 6144) {
    int idx = blockIdx.x * 256 + threadIdx.x;           // 0 .. 1.5M-1
    if (idx < 1048576) {                                // catb: 4M u16, 4 per thread
      int e = idx * 4;
      int row = e >> 10, col = e & 1023;
      int b = row >> 11, t = row & 2047;
      const float* s = (t < 1024) ? &mem[((size_t)(b * 1024 + t)) * 1024 + col]
                                  : &h[((size_t)(b * 1024 + t - 1024)) * 1024 + col];
      float4 v = *(const float4*)s;
      *(ushort4*)&catb[e] = make_ushort4(f2bf(v.x), f2bf(v.y), f2bf(v.z), f2bf(v.w));
    } else {
      int e = (idx - 1048576) * 4;                      // rb: 2M elements
      float4 v = *(const float4*)&r[e];
      *(ushort4*)&rb[e] = make_ushort4(f2bf(v.x), f2bf(v.y), f2bf(v.z), f2bf(v.w));
    }
    return;
  }
  int q = blockIdx.x - 6144;
  int job = q >> 8;
  int tb = q & 255;
  int sr0 = (tb >> 4) * 64, sc0 = (tb & 15) * 64;
  const float* src = (job == 0) ? Wq : (job == 1) ? Wk : (job == 2) ? Wv : (job == 3) ? Wr : Wo;
  int tid = threadIdx.x;
  int rr = tid >> 4, c4 = (tid & 15) * 4;
#pragma unroll
  for (int i = 0; i < 4; ++i) {
    int row = rr + i * 16;
    float4 v = *(const float4*)&src[(size_t)(sr0 + row) * 1024 + sc0 + c4];
    float vv[4] = {v.x, v.y, v.z, v.w};
#pragma unroll
    for (int j = 0; j < 4; ++j) {
      unsigned short hi = f2bf(vv[j]);
      tH[c4 + j][row] = hi;
      if (job == 4) tL[c4 + j][row] = f2bf(vv[j] - bf2f(hi));
    }
  }
  __syncthreads();
  unsigned short* dst = (job == 0) ? wqt : (job == 1) ? wkvt
                      : (job == 2) ? (wkvt + (size_t)1024 * 1024)
                      : (job == 3) ? wrt : wohi;
#pragma unroll
  for (int i = 0; i < 4; ++i) {
    int row = rr + i * 16;
    size_t o = (size_t)(sc0 + row) * 1024 + sr0 + c4;
    *(ushort4*)&dst[o] = make_ushort4(tH[row][c4], tH[row][c4 + 1], tH[row][c4 + 2], tH[row][c4 + 3]);
    if (job == 4)
      *(ushort4*)&wolo[o] = make_ushort4(tL[row][c4], tL[row][c4 + 1], tL[row][c4 + 2], tL[row][c4 + 3]);
  }
}

// ---------------- projection GEMMs (bf16 MFMA, 128x128 tile, BK=32, double-buffered) --
__global__ __launch_bounds__(256) void gemm_all(
    const unsigned short* __restrict__ catb, const unsigned short* __restrict__ rb,
    const unsigned short* __restrict__ wqt, const unsigned short* __restrict__ wkvt,
    const unsigned short* __restrict__ wrt,
    const float* __restrict__ rwb, const float* __restrict__ rrb,
    unsigned short* __restrict__ qwP, unsigned short* __restrict__ qrP,
    unsigned short* __restrict__ kP, unsigned short* __restrict__ vP,
    unsigned short* __restrict__ rP)
{
  __shared__ __align__(16) unsigned short As[2][128 * 32];
  __shared__ __align__(16) unsigned short Bs[2][128 * 32];
  int blk = blockIdx.x, tid = threadIdx.x;
  int job, mb, nb;
  const unsigned short *A, *Bt;
  if (blk < 128)      { job = 0; A = catb; Bt = wqt;  mb = blk >> 3; nb = blk & 7; }
  else if (blk < 640) { job = 1; A = catb; Bt = wkvt; int q = blk - 128; mb = q >> 4; nb = q & 15; }
  else                { job = 2; A = rb;   Bt = wrt;  int q = blk - 640; mb = q >> 3; nb = q & 7; }

  const int w = tid >> 6;
  const int r0 = tid >> 2;                 // chunk0 row (0..63)
  const int c0u = (tid & 3) * 8;           // u16 col offset within 32-wide slab
  int ga_r0 = mb * 128 + r0, ga_r1 = mb * 128 + 64 + r0;
  if (job == 0) {
    ga_r0 = ((ga_r0 >> 10) << 11) + 1024 + (ga_r0 & 1023);
    ga_r1 = ((ga_r1 >> 10) << 11) + 1024 + (ga_r1 & 1023);
  }
  const unsigned short* gA0 = A + (size_t)ga_r0 * 1024 + c0u;
  const unsigned short* gA1 = A + (size_t)ga_r1 * 1024 + c0u;
  const unsigned short* gB0 = Bt + (size_t)(nb * 128 + r0) * 1024 + c0u;
  const unsigned short* gB1 = Bt + (size_t)(nb * 128 + 64 + r0) * 1024 + c0u;

  const int lane = tid & 63;
  const int lc = lane & 15, quad = lane >> 4;
  const int wm = (w & 1) * 64, wn = (w >> 1) * 64;

  auto stage = [&](int k0, int bi) {
    gl2lds16(gA0 + k0, (char*)As[bi] + w * 1024);
    gl2lds16(gA1 + k0, (char*)As[bi] + 4096 + w * 1024);
    gl2lds16(gB0 + k0, (char*)Bs[bi] + w * 1024);
    gl2lds16(gB1 + k0, (char*)Bs[bi] + 4096 + w * 1024);
  };

  f32x4 acc[4][4];
#pragma unroll
  for (int mt = 0; mt < 4; ++mt)
#pragma unroll
    for (int nt = 0; nt < 4; ++nt) { acc[mt][nt][0] = 0.f; acc[mt][nt][1] = 0.f; acc[mt][nt][2] = 0.f; acc[mt][nt][3] = 0.f; }

  stage(0, 0);
  __syncthreads();
  for (int k0 = 0; k0 < 1024; k0 += 32) {
    int cur = (k0 >> 5) & 1;
    if (k0 + 32 < 1024) stage(k0 + 32, cur ^ 1);
    s16x8 af[4], bfr[4];
#pragma unroll
    for (int mt = 0; mt < 4; ++mt) af[mt] = *(const s16x8*)&As[cur][(wm + mt * 16 + lc) * 32 + quad * 8];
#pragma unroll
    for (int nt = 0; nt < 4; ++nt) bfr[nt] = *(const s16x8*)&Bs[cur][(wn + nt * 16 + lc) * 32 + quad * 8];
#pragma unroll
    for (int mt = 0; mt < 4; ++mt)
#pragma unroll
      for (int nt = 0; nt < 4; ++nt) acc[mt][nt] = mfma16(af[mt], bfr[nt], acc[mt][nt]);
    __syncthreads();
  }

#pragma unroll
  for (int mt = 0; mt < 4; ++mt) {
    int t4 = mb * 128 + wm + mt * 16 + quad * 4;
#pragma unroll
    for (int nt = 0; nt < 4; ++nt) {
      int n = nb * 128 + wn + nt * 16 + lc;
      if (job == 0) {
        int hh = n >> 6, dh = n & 63;
        int f = dh >> 5, qd = (dh >> 3) & 3, j = dh & 7;
        float bw = rwb[n], br = rrb[n];
        int bb = t4 >> 10, trow = t4 & 1023;
        size_t tbb = ((((size_t)(bb * NH + hh) * 64 + (trow >> 4)) * 2 + f) * 512) + qd * 128 + j;
        int l0 = trow & 15;
#pragma unroll
        for (int rr = 0; rr < 4; ++rr) {
          qwP[tbb + (l0 + rr) * 8] = f2bf(acc[mt][nt][rr] + bw);
          qrP[tbb + (l0 + rr) * 8] = f2bf(acc[mt][nt][rr] + br);
        }
      } else if (job == 1) {
        int bb = t4 >> 11, t = t4 & 2047;
        if (n < 1024) {
          int hh = n >> 6, dh = n & 63;
          int f = dh >> 5, qd = (dh >> 3) & 3, j = dh & 7;
          size_t tbb = ((((size_t)(bb * NH + hh) * 128 + (t >> 4)) * 2 + f) * 512) + qd * 128 + j;
          int l0 = t & 15;
#pragma unroll
          for (int rr = 0; rr < 4; ++rr)
            kP[tbb + (l0 + rr) * 8] = f2bf(acc[mt][nt][rr]);
        } else {
          int n2 = n - 1024, hh = n2 >> 6, dh = n2 & 63;
          int bhv = bb * NH + hh;
          int kt = t >> 5;
          int ntv = dh >> 4;
          // key-permuted V A-frag: key tau=t&31 sits at lane-quad (tau>>2)&3, elem (tau&3)+4*((tau>>4)&1)
          int lanev = (((t >> 2) & 3) << 4) + (dh & 15);
          int elemv = ((t >> 4) & 1) << 2;          // t4 is a multiple of 4: elems elemv..elemv+3
          ushort4 pk = make_ushort4(f2bf(acc[mt][nt][0]), f2bf(acc[mt][nt][1]),
                                    f2bf(acc[mt][nt][2]), f2bf(acc[mt][nt][3]));
          *(ushort4*)&vP[(((size_t)bhv * 64 + kt) * 4 + ntv) * 512 + lanev * 8 + elemv] = pk;
        }
      } else {
        int hh = n >> 6, dh = n & 63;
        int f = dh >> 5, qd = (dh >> 3) & 3, j = dh & 7;
        size_t tbb = (((size_t)hh * 128 + (t4 >> 4)) * 2 + f) * 512 + qd * 128 + j;
        int l0 = t4 & 15;
#pragma unroll
        for (int rr = 0; rr < 4; ++rr)
          rP[tbb + (l0 + rr) * 8] = f2bf(acc[mt][nt][rr]);
      }
    }
  }
}

// ---------------- fused flash attention with rel-shift (bf16 MFMA) --------------------
// TWO-HALF K processing (halved LDS: 66 KB -> 34 KB). R9 proved the structure correct
// but __launch_bounds__(512,8) strangled the allocator (VGPR=32, 868 MB scratch).
// Round 10: __launch_bounds__(512,6) -> 3 blocks/CU (24 waves, +50% vs R8), VGPR cap ~85.
// qa00/qa01 loaded per-half inside phase 0 (shorter live range).
// Main loop: swapped QK^T (mfma(K,Q)), BD folded into C operand, P lane-local via
// v_cvt_pk_bf16_f32 into key-permuted V tiles, macro unroll-2 with named A/B reg sets.
// XCD-swizzled grid.
#define BDSTR 1060          // u16 row stride: 530 words = 18 mod 32 -> conflict-free-ish b64 reads
#define OSTR 65             // f32 merge-row stride
__global__ __launch_bounds__(512, 6) void attn(
    const unsigned short* __restrict__ qwP, const unsigned short* __restrict__ qrP,
    const unsigned short* __restrict__ kP, const unsigned short* __restrict__ vP,
    const unsigned short* __restrict__ rP,
    unsigned short* __restrict__ avhi, unsigned short* __restrict__ avlo)
{
  __shared__ __align__(16) unsigned short bdS[16 * BDSTR];   // 33920 B
  float* oS = (float*)bdS;                 // merge overlay: [8][16][OSTR] f32 = 33280 B
  float* lS = (float*)bdS + 8 * 16 * OSTR; // [8][16] f32 (33280..33792 B, fits 33920)

  const int tid = threadIdx.x;
  const int w = tid >> 6, lane = tid & 63;
  const int lc = lane & 15, quad = lane >> 4;
  // XCD swizzle: hw block -> semantic block so one (b,h)'s 64 q-tiles share an XCD L2
  const int sem = (blockIdx.x & 7) * 256 + (blockIdx.x >> 3);
  const int is = sem & 63, h = (sem >> 6) & 15, b = sem >> 10;
  const int i0 = is * 16;
  const size_t bh = (size_t)b * NH + h;

  const unsigned short* qwP_p = qwP + bh * 65536;
  const unsigned short* qrP_p = qrP + bh * 65536;
  const unsigned short* kP_p  = kP + bh * 131072;
  const unsigned short* vP_p  = vP + bh * (size_t)KL * DH + lane * 8;
  const unsigned short* rP_p  = rP + (size_t)h * 131072;

  // Q fragments for the main loop (held across both halves)
  s16x8 qwf0 = *(const s16x8*)(qwP_p + is * 1024 + lane * 8);
  s16x8 qwf1 = *(const s16x8*)(qwP_p + is * 1024 + 512 + lane * 8);

  f32x4 O[4];
#pragma unroll
  for (int nt = 0; nt < 4; ++nt) { O[nt][0] = 0.f; O[nt][1] = 0.f; O[nt][2] = 0.f; O[nt][3] = 0.f; }
  float lsumQ = 0.f;

  const unsigned short* bdlane = bdS + lc * BDSTR + quad * 4;   // q-row = lc, keys 4*quad+..
  const int rbq = quad * 4 * BDSTR;        // per-lane phase-0 row base (u16 units)
  const int cmax = 1006 - i0;              // raw row i0+16 only needed at cols <= cmax
  const float E2S = 0.18033688011112042f;  // 0.125 * log2(e)
  const float E2B = -17.312340490667562f;  // -12  * log2(e)

  // A/B named register sets; straight-line macros (no lambdas / pointer params).
  s16x8 ka0A, ka1A, kb0A, kb1A, v0A, v1A, v2A, v3A;
  s16x8 ka0B, ka1B, kb0B, kb1B, v0B, v1B, v2B, v3B;
  uint2 bq0A, bq1A, bq0B, bq1B;

#define LOADC(S, kg, kc) { \
    const unsigned short* kp_ = kP_p + (size_t)((kg) >> 4) * 1024 + lane * 8; \
    ka0##S = *(const s16x8*)kp_; \
    ka1##S = *(const s16x8*)(kp_ + 512); \
    kb0##S = *(const s16x8*)(kp_ + 1024); \
    kb1##S = *(const s16x8*)(kp_ + 1536); \
    const unsigned short* bp_ = vP_p + (size_t)((kg) >> 5) * 2048; \
    v0##S = *(const s16x8*)bp_; \
    v1##S = *(const s16x8*)(bp_ + 512); \
    v2##S = *(const s16x8*)(bp_ + 1024); \
    v3##S = *(const s16x8*)(bp_ + 1536); \
    bq0##S = *(const uint2*)(bdlane + (kc)); \
    bq1##S = *(const uint2*)(bdlane + (kc) + 16); \
  }

#define COMPUTE(S) { \
    f32x4 c_; \
    c_[0] = __builtin_bit_cast(float, bq0##S.x << 16); \
    c_[1] = __builtin_bit_cast(float, bq0##S.x & 0xFFFF0000u); \
    c_[2] = __builtin_bit_cast(float, bq0##S.y << 16); \
    c_[3] = __builtin_bit_cast(float, bq0##S.y & 0xFFFF0000u); \
    c_ = mfma16(ka0##S, qwf0, c_); \
    c_ = mfma16(ka1##S, qwf1, c_); \
    f32x4 d_; \
    d_[0] = __builtin_bit_cast(float, bq1##S.x << 16); \
    d_[1] = __builtin_bit_cast(float, bq1##S.x & 0xFFFF0000u); \
    d_[2] = __builtin_bit_cast(float, bq1##S.y << 16); \
    d_[3] = __builtin_bit_cast(float, bq1##S.y & 0xFFFF0000u); \
    d_ = mfma16(kb0##S, qwf0, d_); \
    d_ = mfma16(kb1##S, qwf1, d_); \
    float p0_[4], p1_[4]; \
    _Pragma("unroll") \
    for (int rr_ = 0; rr_ < 4; ++rr_) { \
      p0_[rr_] = __builtin_amdgcn_exp2f(fmaf(c_[rr_], E2S, E2B)); \
      p1_[rr_] = __builtin_amdgcn_exp2f(fmaf(d_[rr_], E2S, E2B)); \
    } \
    lsumQ += ((p0_[0] + p0_[1]) + (p0_[2] + p0_[3])) + ((p1_[0] + p1_[1]) + (p1_[2] + p1_[3])); \
    unsigned int w0_, w1_, w2_, w3_; \
    asm("v_cvt_pk_bf16_f32 %0, %1, %2" : "=v"(w0_) : "v"(p0_[0]), "v"(p0_[1])); \
    asm("v_cvt_pk_bf16_f32 %0, %1, %2" : "=v"(w1_) : "v"(p0_[2]), "v"(p0_[3])); \
    asm("v_cvt_pk_bf16_f32 %0, %1, %2" : "=v"(w2_) : "v"(p1_[0]), "v"(p1_[1])); \
    asm("v_cvt_pk_bf16_f32 %0, %1, %2" : "=v"(w3_) : "v"(p1_[2]), "v"(p1_[3])); \
    u32x4 pw4_ = {w0_, w1_, w2_, w3_}; \
    s16x8 pf_ = __builtin_bit_cast(s16x8, pw4_); \
    O[0] = mfma16(v0##S, pf_, O[0]); \
    O[1] = mfma16(v1##S, pf_, O[1]); \
    O[2] = mfma16(v2##S, pf_, O[2]); \
    O[3] = mfma16(v3##S, pf_, O[3]); \
  }

#pragma unroll 1
  for (int H = 0; H < 2; ++H) {
    if (H) __syncthreads();                 // all half-0 bdS readers done before overwrite

    // ---- phase 0 (half H): raw BD tiles this half needs, pre-shifted stores ----
    if (H && tid < 16) {                    // diagonal hole (key = q+1025) lives in half 1
      int kz = i0 + tid + 1025;
      if (kz < 2048) bdS[tid * BDSTR + (kz - 1024)] = 0;
    }
    {
      // phase-0 Q fragments: loaded per-half (short live range, saves 8 VGPR in main loop)
      s16x8 qa00 = *(const s16x8*)(qrP_p + is * 1024 + lane * 8);
      s16x8 qa01 = *(const s16x8*)(qrP_p + is * 1024 + 512 + lane * 8);
      int n, xA_hi = 0, xB_lo = 0, xbase = 0;
      if (H == 0) {
        xbase = (1008 - i0) >> 4;
        n = ((2046 - i0) >> 4) - xbase + 1;           // <= 66
      } else {
        xA_hi = (1022 - i0) >> 4;                     // wrap window [0, xA_hi]
        xB_lo = (2032 - i0) >> 4;                     // direct window [xB_lo, 127]
        n = (xA_hi + 1) + (128 - xB_lo);              // <= 66
      }
      s16x8 qa10, qa11;
      if (H) {                                        // 17th-row fragments (half 1 only)
        int r1 = i0 + 16 + lc; if (r1 > 1023) r1 = 1023;
        int off1 = (r1 >> 4) * 1024 + (quad * 16 + (r1 & 15)) * 8;
        qa10 = *(const s16x8*)(qrP_p + off1);
        qa11 = *(const s16x8*)(qrP_p + off1 + 512);
      }
#pragma unroll 1
      for (int j = 0; j < 9; ++j) {
        int t = w + 8 * j;                            // wave-uniform
        if (t >= n) break;
        int xt = (H == 0) ? (xbase + t)
                          : ((t <= xA_hi) ? t : (xB_lo + (t - xA_hi - 1)));
        const unsigned short* rp = rP_p + xt * 1024 + lane * 8;
        s16x8 cf0 = *(const s16x8*)rp;
        s16x8 cf1 = *(const s16x8*)(rp + 512);
        f32x4 c0; c0[0] = 0.f; c0[1] = 0.f; c0[2] = 0.f; c0[3] = 0.f;
        c0 = mfma16(qa00, cf0, c0); c0 = mfma16(qa01, cf1, c0);
        int c = xt * 16 + lc;
        if (H == 0) {
#pragma unroll
          for (int rr = 0; rr < 4; ++rr) {
            int row = quad * 4 + rr;
            int s = c + i0 + row - 1023;              // direct key; this half keeps [0,1024)
            if ((unsigned)s < 1024u)
              bdS[rbq + rr * BDSTR + s] = f2bf(c0[rr]);
          }
        } else {
#pragma unroll
          for (int rr = 0; rr < 4; ++rr) {
            int s = c + i0 + quad * 4 + rr - 1023;
            // s>=1024: direct store at col s-1024; s<0: wrap to row-1 at col s+1024
            // (row-1)*BDSTR + (s+1024) == row*BDSTR + s - 36   [BDSTR=1060]
            int off = (s >= 1024) ? (s - 1024) : (s - 36);
            if (s >= 1024 || (s < 0 && (quad | rr) != 0))
              bdS[rbq + rr * BDSTR + off] = f2bf(c0[rr]);
          }
          if (xt * 16 <= cmax) {                      // 17th row -> row 15 wrap keys
            f32x4 c1; c1[0] = 0.f; c1[1] = 0.f; c1[2] = 0.f; c1[3] = 0.f;
            c1 = mfma16(qa10, cf0, c1); c1 = mfma16(qa11, cf1, c1);
            if (lane < 16) {
              int key2 = c + i0 + 1041;               // always >= 1041 (half 1)
              if (key2 < 2048) bdS[15 * BDSTR + (key2 - 1024)] = f2bf(c1[0]);
            }
          }
        }
      }
    }
    __syncthreads();

    // ---- main split-K (this half): wave w handles keys [1024H + w*128, +128), 4 chunks ----
    const int kg0 = H * 1024 + w * 128;               // global key base (kP/vP)
    const int kc0 = w * 128;                          // bdS column base
    LOADC(A, kg0, kc0)
#pragma unroll 1
    for (int s2 = 0; s2 < 4; s2 += 2) {
      LOADC(B, kg0 + (s2 + 1) * 32, kc0 + (s2 + 1) * 32)
      COMPUTE(A)
      if (s2 < 2) LOADC(A, kg0 + (s2 + 2) * 32, kc0 + (s2 + 2) * 32)
      COMPUTE(B)
    }
  }
#undef LOADC
#undef COMPUTE

  // row-sum over quads (q = lc is lane-local)
  lsumQ += __shfl_xor(lsumQ, 16);
  lsumQ += __shfl_xor(lsumQ, 32);

  // ---- merge: plain sums over 8 waves ----
  __syncthreads();               // all waves done with bdS reads
#pragma unroll
  for (int nt = 0; nt < 4; ++nt)
#pragma unroll
    for (int rr = 0; rr < 4; ++rr)
      oS[(w * 16 + lc) * OSTR + nt * 16 + quad * 4 + rr] = O[nt][rr];
  if (lane < 16) lS[w * 16 + lc] = lsumQ;
  __syncthreads();

  if (tid < 256) {
    int r = tid >> 4, c0 = (tid & 15) * 4;
    float L = 0.f, a0 = 0.f, a1 = 0.f, a2 = 0.f, a3 = 0.f;
#pragma unroll
    for (int wv = 0; wv < 8; ++wv) {
      L += lS[wv * 16 + r];
      const float* op = oS + (wv * 16 + r) * OSTR + c0;
      a0 += op[0]; a1 += op[1]; a2 += op[2]; a3 += op[3];
    }
    float inv = 1.0f / L;
    float v[4] = {a0 * inv, a1 * inv, a2 * inv, a3 * inv};
    unsigned short hi[4], lo[4];
#pragma unroll
    for (int j = 0; j < 4; ++j) {
      hi[j] = f2bf(v[j]);
      lo[j] = f2bf(v[j] - bf2f(hi[j]));
    }
    size_t oidx = ((size_t)(b * QL + i0 + r)) * DM + h * DH + c0;
    *(ushort4*)&avhi[oidx] = make_ushort4(hi[0], hi[1], hi[2], hi[3]);
    *(ushort4*)&avlo[oidx] = make_ushort4(lo[0], lo[1], lo[2], lo[3]);
  }
}

// ---------------- final GEMM: out = av @ Wo, fused 3-segment split-bf16 ----------------
// XCD-swizzled (512 = 8 x 64, bijective): each XCD owns 4 contiguous mb rows -> avhi/avlo
// panels stay L2-local; Wo panels (4 MB total) fit L2 regardless.
__global__ __launch_bounds__(256) void gemm_final(
    const unsigned short* __restrict__ avhi, const unsigned short* __restrict__ avlo,
    const unsigned short* __restrict__ wohi, const unsigned short* __restrict__ wolo,
    float* __restrict__ out)
{
  __shared__ __align__(16) unsigned short S[2][4][64 * 32];   // [buf][op][64][32]
  int tid = threadIdx.x;
  int sem = (blockIdx.x & 7) * 64 + (blockIdx.x >> 3);   // XCD swizzle
  int mb = sem >> 4, nb = sem & 15;    // 32 x 16

  const int w = tid >> 6, lane = tid & 63;
  const int srow = w * 16 + (lane >> 2);
  const int scu = (lane & 3) * 8;
  const size_t arow = (size_t)(mb * 64 + srow) * 1024 + scu;
  const size_t brow = (size_t)(nb * 64 + srow) * 1024 + scu;

  const int lc = lane & 15, quad = lane >> 4;
  const int wm = (w & 1) * 32, wn = (w >> 1) * 32;

  auto stage = [&](int k0, int bi) {
    gl2lds16(avhi + arow + k0, (char*)S[bi][0] + w * 1024);
    gl2lds16(avlo + arow + k0, (char*)S[bi][1] + w * 1024);
    gl2lds16(wohi + brow + k0, (char*)S[bi][2] + w * 1024);
    gl2lds16(wolo + brow + k0, (char*)S[bi][3] + w * 1024);
  };

  f32x4 acc[2][2];
#pragma unroll
  for (int mt = 0; mt < 2; ++mt)
#pragma unroll
    for (int nt = 0; nt < 2; ++nt) { acc[mt][nt][0] = 0.f; acc[mt][nt][1] = 0.f; acc[mt][nt][2] = 0.f; acc[mt][nt][3] = 0.f; }

  stage(0, 0);
  __syncthreads();
  for (int k0 = 0; k0 < 1024; k0 += 32) {
    int cur = (k0 >> 5) & 1;
    if (k0 + 32 < 1024) stage(k0 + 32, cur ^ 1);
    s16x8 ah[2], al[2], bh[2], bl[2];
#pragma unroll
    for (int mt = 0; mt < 2; ++mt) {
      int off = (wm + mt * 16 + lc) * 32 + quad * 8;
      ah[mt] = *(const s16x8*)&S[cur][0][off];
      al[mt] = *(const s16x8*)&S[cur][1][off];
    }
#pragma unroll
    for (int nt = 0; nt < 2; ++nt) {
      int off = (wn + nt * 16 + lc) * 32 + quad * 8;
      bh[nt] = *(const s16x8*)&S[cur][2][off];
      bl[nt] = *(const s16x8*)&S[cur][3][off];
    }
#pragma unroll
    for (int mt = 0; mt < 2; ++mt)
#pragma unroll
      for (int nt = 0; nt < 2; ++nt) {
        acc[mt][nt] = mfma16(ah[mt], bh[nt], acc[mt][nt]);
        acc[mt][nt] = mfma16(ah[mt], bl[nt], acc[mt][nt]);
        acc[mt][nt] = mfma16(al[mt], bh[nt], acc[mt][nt]);
      }
    __syncthreads();
  }

#pragma unroll
  for (int mt = 0; mt < 2; ++mt)
#pragma unroll
    for (int nt = 0; nt < 2; ++nt) {
      int n = nb * 64 + wn + nt * 16 + lc;
#pragma unroll
      for (int rr = 0; rr < 4; ++rr) {
        int m = mb * 64 + wm + mt * 16 + quad * 4 + rr;
        out[(size_t)m * 1024 + n] = acc[mt][nt][rr];
      }
    }
}

extern "C" void kernel_launch(void* const* d_in, const int* in_sizes, int n_in,
                              void* d_out, int out_size, void* d_ws, size_t ws_size,
                              hipStream_t stream) {
  (void)in_sizes; (void)n_in; (void)out_size; (void)ws_size;
  const float* h   = (const float*)d_in[0];
  const float* mem = (const float*)d_in[1];
  const float* r   = (const float*)d_in[2];
  const float* Wq  = (const float*)d_in[3];
  const float* Wk  = (const float*)d_in[4];
  const float* Wv  = (const float*)d_in[5];
  const float* Wr  = (const float*)d_in[6];
  const float* Wo  = (const float*)d_in[7];
  const float* rwb = (const float*)d_in[8];
  const float* rrb = (const float*)d_in[9];
  float* out = (float*)d_out;

  char* ws = (char*)d_ws;
  unsigned short* catb = (unsigned short*)(ws + 0);          // 8 MB
  unsigned short* rb   = (unsigned short*)(ws + 8388608);    // 4 MB
  unsigned short* wqt  = (unsigned short*)(ws + 12582912);   // 2 MB
  unsigned short* wkvt = (unsigned short*)(ws + 14680064);   // 4 MB
  unsigned short* wrt  = (unsigned short*)(ws + 18874368);   // 2 MB
  unsigned short* wohi = (unsigned short*)(ws + 20971520);   // 2 MB
  unsigned short* wolo = (unsigned short*)(ws + 23068672);   // 2 MB
  unsigned short* qwP  = (unsigned short*)(ws + 25165824);   // 4 MB (A-frag packed)
  unsigned short* qrP  = (unsigned short*)(ws + 29360128);   // 4 MB (A-frag packed)
  unsigned short* kPb  = (unsigned short*)(ws + 33554432);   // 8 MB (B-frag packed)
  unsigned short* vPb  = (unsigned short*)(ws + 41943040);   // 8 MB (key-permuted A-frag)
  unsigned short* rPb  = (unsigned short*)(ws + 50331648);   // 4 MB (B-frag packed)
  unsigned short* avhi = (unsigned short*)(ws + 54525952);   // 4 MB
  unsigned short* avlo = (unsigned short*)(ws + 58720256);   // 4 MB

  prep_all<<<7424, 256, 0, stream>>>(h, mem, r, Wq, Wk, Wv, Wr, Wo,
                                     catb, rb, wqt, wkvt, wrt, wohi, wolo);
  gemm_all<<<768, 256, 0, stream>>>(catb, rb, wqt, wkvt, wrt, rwb, rrb,
                                    qwP, qrP, kPb, vPb, rPb);
  attn<<<2048, 512, 0, stream>>>(qwP, qrP, kPb, vPb, rPb, avhi, avlo);
  gemm_final<<<512, 256, 0, stream>>>(avhi, avlo, wohi, wolo, out);
}

// Round 11
// 246.158 us; speedup vs baseline: 1.9317x; 1.6926x over previous
//
#include <hip/hip_runtime.h>

#define DM 1024
#define NH 16
#define DH 64
#define QL 1024
#define KL 2048

typedef short s16x8 __attribute__((ext_vector_type(8)));
typedef float f32x4 __attribute__((ext_vector_type(4)));
typedef unsigned int u32x4 __attribute__((ext_vector_type(4)));

__device__ __forceinline__ unsigned short f2bf(float f) {
  unsigned int u = __builtin_bit_cast(unsigned int, f);
  u += 0x7fffu + ((u >> 16) & 1u);
  return (unsigned short)(u >> 16);
}
__device__ __forceinline__ float bf2f(unsigned short b) {
  unsigned int u = ((unsigned int)b) << 16;
  return __builtin_bit_cast(float, u);
}
__device__ __forceinline__ f32x4 mfma16(s16x8 a, s16x8 b, f32x4 c) {
  return __builtin_amdgcn_mfma_f32_16x16x32_bf16(a, b, c, 0, 0, 0);
}
// async global->LDS, 16B per lane; LDS dest = wave-uniform base + lane*16
__device__ __forceinline__ void gl2lds16(const void* g, void* l) {
  __builtin_amdgcn_global_load_lds(
      (const __attribute__((address_space(1))) unsigned int*)g,
      (__attribute__((address_space(3))) unsigned int*)l, 16, 0, 0);
}

// Fragment-packed layouts (all bf16):
//  qP/qrP: [bh][qt=row/16][f=dim/32][lane=((dim>>3)&3)*16+(row&15)][j=dim&7]   (A-frag)
//  kP:     [bh][kt=key/16][f][lane][j]  (B-frag; lane=((dim>>3)&3)*16+(key&15))
//  rP:     [h][xt=row/16][f][lane][j]   (B-frag)
//  vP:     [bh][kt=key/32][nt=dim/16][lane=((key>>2)&3)*16+(dim&15)][e=(key&3)+4*((key>>4)&1)]
//          (A-frag of PV with keys PERMUTED inside each 32-tile by kappa(quad,e)=4q+(e&3)+16(e>>2),
//           so swapped-QK's lane-local P feeds PV's B operand with NO cross-lane movement.)

// ---------------- fused prep: blocks 0..6143 input conversion, 6144..7423 weights ------
__global__ __launch_bounds__(256) void prep_all(
    const float* __restrict__ h, const float* __restrict__ mem, const float* __restrict__ r,
    const float* __restrict__ Wq, const float* __restrict__ Wk, const float* __restrict__ Wv,
    const float* __restrict__ Wr, const float* __restrict__ Wo,
    unsigned short* __restrict__ catb, unsigned short* __restrict__ rb,
    unsigned short* __restrict__ wqt, unsigned short* __restrict__ wkvt,
    unsigned short* __restrict__ wrt,
    unsigned short* __restrict__ wohi, unsigned short* __restrict__ wolo)
{
  __shared__ unsigned short tH[64][72];
  __shared__ unsigned short tL[64][72];
  if (blockIdx.x < 6144) {
    int idx = blockIdx.x * 256 + threadIdx.x;           // 0 .. 1.5M-1
    if (idx < 1048576) {                                // catb: 4M u16, 4 per thread
      int e = idx * 4;
      int row = e >> 10, col = e & 1023;
      int b = row >> 11, t = row & 2047;
      const float* s = (t < 1024) ? &mem[((size_t)(b * 1024 + t)) * 1024 + col]
                                  : &h[((size_t)(b * 1024 + t - 1024)) * 1024 + col];
      float4 v = *(const float4*)s;
      *(ushort4*)&catb[e] = make_ushort4(f2bf(v.x), f2bf(v.y), f2bf(v.z), f2bf(v.w));
    } else {
      int e = (idx - 1048576) * 4;                      // rb: 2M elements
      float4 v = *(const float4*)&r[e];
      *(ushort4*)&rb[e] = make_ushort4(f2bf(v.x), f2bf(v.y), f2bf(v.z), f2bf(v.w));
    }
    return;
  }
  int q = blockIdx.x - 6144;
  int job = q >> 8;
  int tb = q & 255;
  int sr0 = (tb >> 4) * 64, sc0 = (tb & 15) * 64;
  const float* src = (job == 0) ? Wq : (job == 1) ? Wk : (job == 2) ? Wv : (job == 3) ? Wr : Wo;
  int tid = threadIdx.x;
  int rr = tid >> 4, c4 = (tid & 15) * 4;
#pragma unroll
  for (int i = 0; i < 4; ++i) {
    int row = rr + i * 16;
    float4 v = *(const float4*)&src[(size_t)(sr0 + row) * 1024 + sc0 + c4];
    float vv[4] = {v.x, v.y, v.z, v.w};
#pragma unroll
    for (int j = 0; j < 4; ++j) {
      unsigned short hi = f2bf(vv[j]);
      tH[c4 + j][row] = hi;
      if (job == 4) tL[c4 + j][row] = f2bf(vv[j] - bf2f(hi));
    }
  }
  __syncthreads();
  unsigned short* dst = (job == 0) ? wqt : (job == 1) ? wkvt
                      : (job == 2) ? (wkvt + (size_t)1024 * 1024)
                      : (job == 3) ? wrt : wohi;
#pragma unroll
  for (int i = 0; i < 4; ++i) {
    int row = rr + i * 16;
    size_t o = (size_t)(sc0 + row) * 1024 + sr0 + c4;
    *(ushort4*)&dst[o] = make_ushort4(tH[row][c4], tH[row][c4 + 1], tH[row][c4 + 2], tH[row][c4 + 3]);
    if (job == 4)
      *(ushort4*)&wolo[o] = make_ushort4(tL[row][c4], tL[row][c4 + 1], tL[row][c4 + 2], tL[row][c4 + 3]);
  }
}

// ---------------- projection GEMMs (bf16 MFMA, 128x128 tile, BK=32, double-buffered) --
__global__ __launch_bounds__(256) void gemm_all(
    const unsigned short* __restrict__ catb, const unsigned short* __restrict__ rb,
    const unsigned short* __restrict__ wqt, const unsigned short* __restrict__ wkvt,
    const unsigned short* __restrict__ wrt,
    const float* __restrict__ rwb, const float* __restrict__ rrb,
    unsigned short* __restrict__ qwP, unsigned short* __restrict__ qrP,
    unsigned short* __restrict__ kP, unsigned short* __restrict__ vP,
    unsigned short* __restrict__ rP)
{
  __shared__ __align__(16) unsigned short As[2][128 * 32];
  __shared__ __align__(16) unsigned short Bs[2][128 * 32];
  int blk = blockIdx.x, tid = threadIdx.x;
  int job, mb, nb;
  const unsigned short *A, *Bt;
  if (blk < 128)      { job = 0; A = catb; Bt = wqt;  mb = blk >> 3; nb = blk & 7; }
  else if (blk < 640) { job = 1; A = catb; Bt = wkvt; int q = blk - 128; mb = q >> 4; nb = q & 15; }
  else                { job = 2; A = rb;   Bt = wrt;  int q = blk - 640; mb = q >> 3; nb = q & 7; }

  const int w = tid >> 6;
  const int r0 = tid >> 2;                 // chunk0 row (0..63)
  const int c0u = (tid & 3) * 8;           // u16 col offset within 32-wide slab
  int ga_r0 = mb * 128 + r0, ga_r1 = mb * 128 + 64 + r0;
  if (job == 0) {
    ga_r0 = ((ga_r0 >> 10) << 11) + 1024 + (ga_r0 & 1023);
    ga_r1 = ((ga_r1 >> 10) << 11) + 1024 + (ga_r1 & 1023);
  }
  const unsigned short* gA0 = A + (size_t)ga_r0 * 1024 + c0u;
  const unsigned short* gA1 = A + (size_t)ga_r1 * 1024 + c0u;
  const unsigned short* gB0 = Bt + (size_t)(nb * 128 + r0) * 1024 + c0u;
  const unsigned short* gB1 = Bt + (size_t)(nb * 128 + 64 + r0) * 1024 + c0u;

  const int lane = tid & 63;
  const int lc = lane & 15, quad = lane >> 4;
  const int wm = (w & 1) * 64, wn = (w >> 1) * 64;

  auto stage = [&](int k0, int bi) {
    gl2lds16(gA0 + k0, (char*)As[bi] + w * 1024);
    gl2lds16(gA1 + k0, (char*)As[bi] + 4096 + w * 1024);
    gl2lds16(gB0 + k0, (char*)Bs[bi] + w * 1024);
    gl2lds16(gB1 + k0, (char*)Bs[bi] + 4096 + w * 1024);
  };

  f32x4 acc[4][4];
#pragma unroll
  for (int mt = 0; mt < 4; ++mt)
#pragma unroll
    for (int nt = 0; nt < 4; ++nt) { acc[mt][nt][0] = 0.f; acc[mt][nt][1] = 0.f; acc[mt][nt][2] = 0.f; acc[mt][nt][3] = 0.f; }

  stage(0, 0);
  __syncthreads();
  for (int k0 = 0; k0 < 1024; k0 += 32) {
    int cur = (k0 >> 5) & 1;
    if (k0 + 32 < 1024) stage(k0 + 32, cur ^ 1);
    s16x8 af[4], bfr[4];
#pragma unroll
    for (int mt = 0; mt < 4; ++mt) af[mt] = *(const s16x8*)&As[cur][(wm + mt * 16 + lc) * 32 + quad * 8];
#pragma unroll
    for (int nt = 0; nt < 4; ++nt) bfr[nt] = *(const s16x8*)&Bs[cur][(wn + nt * 16 + lc) * 32 + quad * 8];
#pragma unroll
    for (int mt = 0; mt < 4; ++mt)
#pragma unroll
      for (int nt = 0; nt < 4; ++nt) acc[mt][nt] = mfma16(af[mt], bfr[nt], acc[mt][nt]);
    __syncthreads();
  }

#pragma unroll
  for (int mt = 0; mt < 4; ++mt) {
    int t4 = mb * 128 + wm + mt * 16 + quad * 4;
#pragma unroll
    for (int nt = 0; nt < 4; ++nt) {
      int n = nb * 128 + wn + nt * 16 + lc;
      if (job == 0) {
        int hh = n >> 6, dh = n & 63;
        int f = dh >> 5, qd = (dh >> 3) & 3, j = dh & 7;
        float bw = rwb[n], br = rrb[n];
        int bb = t4 >> 10, trow = t4 & 1023;
        size_t tbb = ((((size_t)(bb * NH + hh) * 64 + (trow >> 4)) * 2 + f) * 512) + qd * 128 + j;
        int l0 = trow & 15;
#pragma unroll
        for (int rr = 0; rr < 4; ++rr) {
          qwP[tbb + (l0 + rr) * 8] = f2bf(acc[mt][nt][rr] + bw);
          qrP[tbb + (l0 + rr) * 8] = f2bf(acc[mt][nt][rr] + br);
        }
      } else if (job == 1) {
        int bb = t4 >> 11, t = t4 & 2047;
        if (n < 1024) {
          int hh = n >> 6, dh = n & 63;
          int f = dh >> 5, qd = (dh >> 3) & 3, j = dh & 7;
          size_t tbb = ((((size_t)(bb * NH + hh) * 128 + (t >> 4)) * 2 + f) * 512) + qd * 128 + j;
          int l0 = t & 15;
#pragma unroll
          for (int rr = 0; rr < 4; ++rr)
            kP[tbb + (l0 + rr) * 8] = f2bf(acc[mt][nt][rr]);
        } else {
          int n2 = n - 1024, hh = n2 >> 6, dh = n2 & 63;
          int bhv = bb * NH + hh;
          int kt = t >> 5;
          int ntv = dh >> 4;
          // key-permuted V A-frag: key tau=t&31 sits at lane-quad (tau>>2)&3, elem (tau&3)+4*((tau>>4)&1)
          int lanev = (((t >> 2) & 3) << 4) + (dh & 15);
          int elemv = ((t >> 4) & 1) << 2;          // t4 is a multiple of 4: elems elemv..elemv+3
          ushort4 pk = make_ushort4(f2bf(acc[mt][nt][0]), f2bf(acc[mt][nt][1]),
                                    f2bf(acc[mt][nt][2]), f2bf(acc[mt][nt][3]));
          *(ushort4*)&vP[(((size_t)bhv * 64 + kt) * 4 + ntv) * 512 + lanev * 8 + elemv] = pk;
        }
      } else {
        int hh = n >> 6, dh = n & 63;
        int f = dh >> 5, qd = (dh >> 3) & 3, j = dh & 7;
        size_t tbb = (((size_t)hh * 128 + (t4 >> 4)) * 2 + f) * 512 + qd * 128 + j;
        int l0 = t4 & 15;
#pragma unroll
        for (int rr = 0; rr < 4; ++rr)
          rP[tbb + (l0 + rr) * 8] = f2bf(acc[mt][nt][rr]);
      }
    }
  }
}

// ---------------- fused flash attention with rel-shift (bf16 MFMA) --------------------
// TWO-HALF K processing (halved LDS: 66 KB -> 34 KB) at __launch_bounds__(512,6)
// -> 3 blocks/CU (24 waves, +50% TLP vs R8's 2 blocks). R9/R10 showed the unroll-2
// body spills under the 6-wave register budget (unified VGPR+AGPR), so the main loop
// is the R4-style ROLLING single-operand-set prefetch (proven 52-VGPR shape).
// Phase 0 per half computes only the raw-BD windows that half needs (verified R9/R10).
// Main loop: swapped QK^T (mfma(K,Q)), BD folded into C operand, P lane-local via
// v_cvt_pk_bf16_f32 into key-permuted V tiles. XCD-swizzled grid.
#define BDSTR 1060          // u16 row stride
#define OSTR 65             // f32 merge-row stride
__global__ __launch_bounds__(512, 6) void attn(
    const unsigned short* __restrict__ qwP, const unsigned short* __restrict__ qrP,
    const unsigned short* __restrict__ kP, const unsigned short* __restrict__ vP,
    const unsigned short* __restrict__ rP,
    unsigned short* __restrict__ avhi, unsigned short* __restrict__ avlo)
{
  __shared__ __align__(16) unsigned short bdS[16 * BDSTR];   // 33920 B
  float* oS = (float*)bdS;                 // merge overlay: [8][16][OSTR] f32 = 33280 B
  float* lS = (float*)bdS + 8 * 16 * OSTR; // [8][16] f32 (33280..33792 B, fits 33920)

  const int tid = threadIdx.x;
  const int w = tid >> 6, lane = tid & 63;
  const int lc = lane & 15, quad = lane >> 4;
  // XCD swizzle: hw block -> semantic block so one (b,h)'s 64 q-tiles share an XCD L2
  const int sem = (blockIdx.x & 7) * 256 + (blockIdx.x >> 3);
  const int is = sem & 63, h = (sem >> 6) & 15, b = sem >> 10;
  const int i0 = is * 16;
  const size_t bh = (size_t)b * NH + h;

  const unsigned short* qwP_p = qwP + bh * 65536;
  const unsigned short* qrP_p = qrP + bh * 65536;
  const unsigned short* kP_p  = kP + bh * 131072;
  const unsigned short* vP_p  = vP + bh * (size_t)KL * DH + lane * 8;
  const unsigned short* rP_p  = rP + (size_t)h * 131072;

  // Q fragments for the main loop (held across both halves)
  s16x8 qwf0 = *(const s16x8*)(qwP_p + is * 1024 + lane * 8);
  s16x8 qwf1 = *(const s16x8*)(qwP_p + is * 1024 + 512 + lane * 8);

  f32x4 O[4];
#pragma unroll
  for (int nt = 0; nt < 4; ++nt) { O[nt][0] = 0.f; O[nt][1] = 0.f; O[nt][2] = 0.f; O[nt][3] = 0.f; }
  float lsumQ = 0.f;

  const unsigned short* bdlane = bdS + lc * BDSTR + quad * 4;   // q-row = lc, keys 4*quad+..
  const int rbq = quad * 4 * BDSTR;        // per-lane phase-0 row base (u16 units)
  const int cmax = 1006 - i0;              // raw row i0+16 only needed at cols <= cmax
  const float E2S = 0.18033688011112042f;  // 0.125 * log2(e)
  const float E2B = -17.312340490667562f;  // -12  * log2(e)

  auto loadK4 = [&](int k0, s16x8& a0, s16x8& a1, s16x8& b0, s16x8& b1) {
    const unsigned short* kp = kP_p + (size_t)(k0 >> 4) * 1024 + lane * 8;
    a0 = *(const s16x8*)kp;
    a1 = *(const s16x8*)(kp + 512);
    b0 = *(const s16x8*)(kp + 1024);
    b1 = *(const s16x8*)(kp + 1536);
  };
  auto loadV4 = [&](int k0, s16x8& x0, s16x8& x1, s16x8& x2, s16x8& x3) {
    const unsigned short* bp = vP_p + (size_t)(k0 >> 5) * 2048;   // 4*512 per 32-key tile
    x0 = *(const s16x8*)bp;
    x1 = *(const s16x8*)(bp + 512);
    x2 = *(const s16x8*)(bp + 1024);
    x3 = *(const s16x8*)(bp + 1536);
  };

#pragma unroll 1
  for (int H = 0; H < 2; ++H) {
    if (H) __syncthreads();                 // all half-0 bdS readers done before overwrite

    // ---- phase 0 (half H): raw BD tiles this half needs, pre-shifted stores ----
    if (H && tid < 16) {                    // diagonal hole (key = q+1025) lives in half 1
      int kz = i0 + tid + 1025;
      if (kz < 2048) bdS[tid * BDSTR + (kz - 1024)] = 0;
    }
    {
      // phase-0 Q fragments: loaded per-half (short live range)
      s16x8 qa00 = *(const s16x8*)(qrP_p + is * 1024 + lane * 8);
      s16x8 qa01 = *(const s16x8*)(qrP_p + is * 1024 + 512 + lane * 8);
      int n, xA_hi = 0, xB_lo = 0, xbase = 0;
      if (H == 0) {
        xbase = (1008 - i0) >> 4;
        n = ((2046 - i0) >> 4) - xbase + 1;           // <= 66
      } else {
        xA_hi = (1022 - i0) >> 4;                     // wrap window [0, xA_hi]
        xB_lo = (2032 - i0) >> 4;                     // direct window [xB_lo, 127]
        n = (xA_hi + 1) + (128 - xB_lo);              // <= 66
      }
      s16x8 qa10, qa11;
      if (H) {                                        // 17th-row fragments (half 1 only)
        int r1 = i0 + 16 + lc; if (r1 > 1023) r1 = 1023;
        int off1 = (r1 >> 4) * 1024 + (quad * 16 + (r1 & 15)) * 8;
        qa10 = *(const s16x8*)(qrP_p + off1);
        qa11 = *(const s16x8*)(qrP_p + off1 + 512);
      }
#pragma unroll 1
      for (int j = 0; j < 9; ++j) {
        int t = w + 8 * j;                            // wave-uniform
        if (t >= n) break;
        int xt = (H == 0) ? (xbase + t)
                          : ((t <= xA_hi) ? t : (xB_lo + (t - xA_hi - 1)));
        const unsigned short* rp = rP_p + xt * 1024 + lane * 8;
        s16x8 cf0 = *(const s16x8*)rp;
        s16x8 cf1 = *(const s16x8*)(rp + 512);
        f32x4 c0; c0[0] = 0.f; c0[1] = 0.f; c0[2] = 0.f; c0[3] = 0.f;
        c0 = mfma16(qa00, cf0, c0); c0 = mfma16(qa01, cf1, c0);
        int c = xt * 16 + lc;
        if (H == 0) {
#pragma unroll
          for (int rr = 0; rr < 4; ++rr) {
            int row = quad * 4 + rr;
            int s = c + i0 + row - 1023;              // direct key; this half keeps [0,1024)
            if ((unsigned)s < 1024u)
              bdS[rbq + rr * BDSTR + s] = f2bf(c0[rr]);
          }
        } else {
#pragma unroll
          for (int rr = 0; rr < 4; ++rr) {
            int s = c + i0 + quad * 4 + rr - 1023;
            // s>=1024: direct store at col s-1024; s<0: wrap to row-1 at col s+1024
            // (row-1)*BDSTR + (s+1024) == row*BDSTR + s - 36   [BDSTR=1060]
            int off = (s >= 1024) ? (s - 1024) : (s - 36);
            if (s >= 1024 || (s < 0 && (quad | rr) != 0))
              bdS[rbq + rr * BDSTR + off] = f2bf(c0[rr]);
          }
          if (xt * 16 <= cmax) {                      // 17th row -> row 15 wrap keys
            f32x4 c1; c1[0] = 0.f; c1[1] = 0.f; c1[2] = 0.f; c1[3] = 0.f;
            c1 = mfma16(qa10, cf0, c1); c1 = mfma16(qa11, cf1, c1);
            if (lane < 16) {
              int key2 = c + i0 + 1041;               // always >= 1041 (half 1)
              if (key2 < 2048) bdS[15 * BDSTR + (key2 - 1024)] = f2bf(c1[0]);
            }
          }
        }
      }
    }
    __syncthreads();

    // ---- main split-K (this half): wave w handles keys [1024H + w*128, +128), 4 chunks,
    //      R4-style rolling prefetch (single operand set + next-set temporaries) ----
    const int kg0 = H * 1024 + w * 128;               // global key base (kP/vP)
    const int kc0 = w * 128;                          // bdS column base
    s16x8 ka0, ka1, kb0, kb1, v0, v1, v2, v3;
    uint2 bq0 = *(const uint2*)(bdlane + kc0);
    uint2 bq1 = *(const uint2*)(bdlane + kc0 + 16);
    loadK4(kg0, ka0, ka1, kb0, kb1);
    loadV4(kg0, v0, v1, v2, v3);

#pragma unroll 1
    for (int s = 0; s < 4; ++s) {
      const int dn = (s < 3) ? (s + 1) * 32 : s * 32; // clamp: last prefetch re-reads
      uint2 nq0 = *(const uint2*)(bdlane + kc0 + dn);
      uint2 nq1 = *(const uint2*)(bdlane + kc0 + dn + 16);
      s16x8 na0, na1, nb0, nb1;  loadK4(kg0 + dn, na0, na1, nb0, nb1);
      s16x8 nv0, nv1, nv2, nv3;  loadV4(kg0 + dn, nv0, nv1, nv2, nv3);

      // swapped QK^T, BD folded into the C operand (bf16 unpack = shift/mask)
      f32x4 c;
      c[0] = __builtin_bit_cast(float, bq0.x << 16);
      c[1] = __builtin_bit_cast(float, bq0.x & 0xFFFF0000u);
      c[2] = __builtin_bit_cast(float, bq0.y << 16);
      c[3] = __builtin_bit_cast(float, bq0.y & 0xFFFF0000u);
      c = mfma16(ka0, qwf0, c);
      c = mfma16(ka1, qwf1, c);
      f32x4 d;
      d[0] = __builtin_bit_cast(float, bq1.x << 16);
      d[1] = __builtin_bit_cast(float, bq1.x & 0xFFFF0000u);
      d[2] = __builtin_bit_cast(float, bq1.y << 16);
      d[3] = __builtin_bit_cast(float, bq1.y & 0xFFFF0000u);
      d = mfma16(kb0, qwf0, d);
      d = mfma16(kb1, qwf1, d);

      float p0[4], p1[4];
#pragma unroll
      for (int rr = 0; rr < 4; ++rr) {
        p0[rr] = __builtin_amdgcn_exp2f(fmaf(c[rr], E2S, E2B));
        p1[rr] = __builtin_amdgcn_exp2f(fmaf(d[rr], E2S, E2B));
      }
      lsumQ += ((p0[0] + p0[1]) + (p0[2] + p0[3])) + ((p1[0] + p1[1]) + (p1[2] + p1[3]));

      // pack P to bf16 in e-order (rr then t): matches vP's key permutation kappa(quad,e)
      unsigned int w0, w1, w2, w3;
      asm("v_cvt_pk_bf16_f32 %0, %1, %2" : "=v"(w0) : "v"(p0[0]), "v"(p0[1]));
      asm("v_cvt_pk_bf16_f32 %0, %1, %2" : "=v"(w1) : "v"(p0[2]), "v"(p0[3]));
      asm("v_cvt_pk_bf16_f32 %0, %1, %2" : "=v"(w2) : "v"(p1[0]), "v"(p1[1]));
      asm("v_cvt_pk_bf16_f32 %0, %1, %2" : "=v"(w3) : "v"(p1[2]), "v"(p1[3]));
      u32x4 pw4 = {w0, w1, w2, w3};
      s16x8 pf = __builtin_bit_cast(s16x8, pw4);

      O[0] = mfma16(v0, pf, O[0]);     // O^T accumulate: col = q-row, rows = dim
      O[1] = mfma16(v1, pf, O[1]);
      O[2] = mfma16(v2, pf, O[2]);
      O[3] = mfma16(v3, pf, O[3]);

      bq0 = nq0; bq1 = nq1;
      ka0 = na0; ka1 = na1; kb0 = nb0; kb1 = nb1;
      v0 = nv0; v1 = nv1; v2 = nv2; v3 = nv3;
    }
  }

  // row-sum over quads (q = lc is lane-local)
  lsumQ += __shfl_xor(lsumQ, 16);
  lsumQ += __shfl_xor(lsumQ, 32);

  // ---- merge: plain sums over 8 waves ----
  __syncthreads();               // all waves done with bdS reads
#pragma unroll
  for (int nt = 0; nt < 4; ++nt)
#pragma unroll
    for (int rr = 0; rr < 4; ++rr)
      oS[(w * 16 + lc) * OSTR + nt * 16 + quad * 4 + rr] = O[nt][rr];
  if (lane < 16) lS[w * 16 + lc] = lsumQ;
  __syncthreads();

  if (tid < 256) {
    int r = tid >> 4, c0 = (tid & 15) * 4;
    float L = 0.f, a0 = 0.f, a1 = 0.f, a2 = 0.f, a3 = 0.f;
#pragma unroll
    for (int wv = 0; wv < 8; ++wv) {
      L += lS[wv * 16 + r];
      const float* op = oS + (wv * 16 + r) * OSTR + c0;
      a0 += op[0]; a1 += op[1]; a2 += op[2]; a3 += op[3];
    }
    float inv = 1.0f / L;
    float v[4] = {a0 * inv, a1 * inv, a2 * inv, a3 * inv};
    unsigned short hi[4], lo[4];
#pragma unroll
    for (int j = 0; j < 4; ++j) {
      hi[j] = f2bf(v[j]);
      lo[j] = f2bf(v[j] - bf2f(hi[j]));
    }
    size_t oidx = ((size_t)(b * QL + i0 + r)) * DM + h * DH + c0;
    *(ushort4*)&avhi[oidx] = make_ushort4(hi[0], hi[1], hi[2], hi[3]);
    *(ushort4*)&avlo[oidx] = make_ushort4(lo[0], lo[1], lo[2], lo[3]);
  }
}

// ---------------- final GEMM: out = av @ Wo, fused 3-segment split-bf16 ----------------
// XCD-swizzled (512 = 8 x 64, bijective): each XCD owns 4 contiguous mb rows -> avhi/avlo
// panels stay L2-local; Wo panels (4 MB total) fit L2 regardless.
__global__ __launch_bounds__(256) void gemm_final(
    const unsigned short* __restrict__ avhi, const unsigned short* __restrict__ avlo,
    const unsigned short* __restrict__ wohi, const unsigned short* __restrict__ wolo,
    float* __restrict__ out)
{
  __shared__ __align__(16) unsigned short S[2][4][64 * 32];   // [buf][op][64][32]
  int tid = threadIdx.x;
  int sem = (blockIdx.x & 7) * 64 + (blockIdx.x >> 3);   // XCD swizzle
  int mb = sem >> 4, nb = sem & 15;    // 32 x 16

  const int w = tid >> 6, lane = tid & 63;
  const int srow = w * 16 + (lane >> 2);
  const int scu = (lane & 3) * 8;
  const size_t arow = (size_t)(mb * 64 + srow) * 1024 + scu;
  const size_t brow = (size_t)(nb * 64 + srow) * 1024 + scu;

  const int lc = lane & 15, quad = lane >> 4;
  const int wm = (w & 1) * 32, wn = (w >> 1) * 32;

  auto stage = [&](int k0, int bi) {
    gl2lds16(avhi + arow + k0, (char*)S[bi][0] + w * 1024);
    gl2lds16(avlo + arow + k0, (char*)S[bi][1] + w * 1024);
    gl2lds16(wohi + brow + k0, (char*)S[bi][2] + w * 1024);
    gl2lds16(wolo + brow + k0, (char*)S[bi][3] + w * 1024);
  };

  f32x4 acc[2][2];
#pragma unroll
  for (int mt = 0; mt < 2; ++mt)
#pragma unroll
    for (int nt = 0; nt < 2; ++nt) { acc[mt][nt][0] = 0.f; acc[mt][nt][1] = 0.f; acc[mt][nt][2] = 0.f; acc[mt][nt][3] = 0.f; }

  stage(0, 0);
  __syncthreads();
  for (int k0 = 0; k0 < 1024; k0 += 32) {
    int cur = (k0 >> 5) & 1;
    if (k0 + 32 < 1024) stage(k0 + 32, cur ^ 1);
    s16x8 ah[2], al[2], bh[2], bl[2];
#pragma unroll
    for (int mt = 0; mt < 2; ++mt) {
      int off = (wm + mt * 16 + lc) * 32 + quad * 8;
      ah[mt] = *(const s16x8*)&S[cur][0][off];
      al[mt] = *(const s16x8*)&S[cur][1][off];
    }
#pragma unroll
    for (int nt = 0; nt < 2; ++nt) {
      int off = (wn + nt * 16 + lc) * 32 + quad * 8;
      bh[nt] = *(const s16x8*)&S[cur][2][off];
      bl[nt] = *(const s16x8*)&S[cur][3][off];
    }
#pragma unroll
    for (int mt = 0; mt < 2; ++mt)
#pragma unroll
      for (int nt = 0; nt < 2; ++nt) {
        acc[mt][nt] = mfma16(ah[mt], bh[nt], acc[mt][nt]);
        acc[mt][nt] = mfma16(ah[mt], bl[nt], acc[mt][nt]);
        acc[mt][nt] = mfma16(al[mt], bh[nt], acc[mt][nt]);
      }
    __syncthreads();
  }

#pragma unroll
  for (int mt = 0; mt < 2; ++mt)
#pragma unroll
    for (int nt = 0; nt < 2; ++nt) {
      int n = nb * 64 + wn + nt * 16 + lc;
#pragma unroll
      for (int rr = 0; rr < 4; ++rr) {
        int m = mb * 64 + wm + mt * 16 + quad * 4 + rr;
        out[(size_t)m * 1024 + n] = acc[mt][nt][rr];
      }
    }
}

extern "C" void kernel_launch(void* const* d_in, const int* in_sizes, int n_in,
                              void* d_out, int out_size, void* d_ws, size_t ws_size,
                              hipStream_t stream) {
  (void)in_sizes; (void)n_in; (void)out_size; (void)ws_size;
  const float* h   = (const float*)d_in[0];
  const float* mem = (const float*)d_in[1];
  const float* r   = (const float*)d_in[2];
  const float* Wq  = (const float*)d_in[3];
  const float* Wk  = (const float*)d_in[4];
  const float* Wv  = (const float*)d_in[5];
  const float* Wr  = (const float*)d_in[6];
  const float* Wo  = (const float*)d_in[7];
  const float* rwb = (const float*)d_in[8];
  const float* rrb = (const float*)d_in[9];
  float* out = (float*)d_out;

  char* ws = (char*)d_ws;
  unsigned short* catb = (unsigned short*)(ws + 0);          // 8 MB
  unsigned short* rb   = (unsigned short*)(ws + 8388608);    // 4 MB
  unsigned short* wqt  = (unsigned short*)(ws + 12582912);   // 2 MB
  unsigned short* wkvt = (unsigned short*)(ws + 14680064);   // 4 MB
  unsigned short* wrt  = (unsigned short*)(ws + 18874368);   // 2 MB
  unsigned short* wohi = (unsigned short*)(ws + 20971520);   // 2 MB
  unsigned short* wolo = (unsigned short*)(ws + 23068672);   // 2 MB
  unsigned short* qwP  = (unsigned short*)(ws + 25165824);   // 4 MB (A-frag packed)
  unsigned short* qrP  = (unsigned short*)(ws + 29360128);   // 4 MB (A-frag packed)
  unsigned short* kPb  = (unsigned short*)(ws + 33554432);   // 8 MB (B-frag packed)
  unsigned short* vPb  = (unsigned short*)(ws + 41943040);   // 8 MB (key-permuted A-frag)
  unsigned short* rPb  = (unsigned short*)(ws + 50331648);   // 4 MB (B-frag packed)
  unsigned short* avhi = (unsigned short*)(ws + 54525952);   // 4 MB
  unsigned short* avlo = (unsigned short*)(ws + 58720256);   // 4 MB

  prep_all<<<7424, 256, 0, stream>>>(h, mem, r, Wq, Wk, Wv, Wr, Wo,
                                     catb, rb, wqt, wkvt, wrt, wohi, wolo);
  gemm_all<<<768, 256, 0, stream>>>(catb, rb, wqt, wkvt, wrt, rwb, rrb,
                                    qwP, qrP, kPb, vPb, rPb);
  attn<<<2048, 512, 0, stream>>>(qwP, qrP, kPb, vPb, rPb, avhi, avlo);
  gemm_final<<<512, 256, 0, stream>>>(avhi, avlo, wohi, wolo, out);
}

// Round 12
// 235.588 us; speedup vs baseline: 2.0183x; 1.0449x over previous
//
#include <hip/hip_runtime.h>

#define DM 1024
#define NH 16
#define DH 64
#define QL 1024
#define KL 2048

typedef short s16x8 __attribute__((ext_vector_type(8)));
typedef float f32x4 __attribute__((ext_vector_type(4)));
typedef unsigned int u32x4 __attribute__((ext_vector_type(4)));

__device__ __forceinline__ unsigned short f2bf(float f) {
  unsigned int u = __builtin_bit_cast(unsigned int, f);
  u += 0x7fffu + ((u >> 16) & 1u);
  return (unsigned short)(u >> 16);
}
__device__ __forceinline__ float bf2f(unsigned short b) {
  unsigned int u = ((unsigned int)b) << 16;
  return __builtin_bit_cast(float, u);
}
__device__ __forceinline__ f32x4 mfma16(s16x8 a, s16x8 b, f32x4 c) {
  return __builtin_amdgcn_mfma_f32_16x16x32_bf16(a, b, c, 0, 0, 0);
}
// async global->LDS, 16B per lane; LDS dest = wave-uniform base + lane*16
__device__ __forceinline__ void gl2lds16(const void* g, void* l) {
  __builtin_amdgcn_global_load_lds(
      (const __attribute__((address_space(1))) unsigned int*)g,
      (__attribute__((address_space(3))) unsigned int*)l, 16, 0, 0);
}

// Fragment-packed layouts (all bf16):
//  qP/qrP: [bh][qt=row/16][f=dim/32][lane=((dim>>3)&3)*16+(row&15)][j=dim&7]   (A-frag)
//  kP:     [bh][kt=key/16][f][lane][j]  (B-frag; lane=((dim>>3)&3)*16+(key&15))
//  rP:     [h][xt=row/16][f][lane][j]   (B-frag)
//  vP:     [bh][kt=key/32][nt=dim/16][lane=((key>>2)&3)*16+(dim&15)][e=(key&3)+4*((key>>4)&1)]
//          (A-frag of PV with keys PERMUTED inside each 32-tile by kappa(quad,e)=4q+(e&3)+16(e>>2),
//           so swapped-QK's lane-local P feeds PV's B operand with NO cross-lane movement.)
//
// Occupancy note (R9-R11 lesson): gfx950 occupancy rungs are total-regs<=64 -> 8 waves/SIMD,
// <=128 -> 4 waves/SIMD (unified VGPR+AGPR). The attn body needs ~80 total, so it runs at
// 4 waves/SIMD regardless of LDS; bound(512,4) + 66KB LDS is the right operating point.

// ---------------- fused prep: blocks 0..6143 input conversion, 6144..7423 weights ------
__global__ __launch_bounds__(256) void prep_all(
    const float* __restrict__ h, const float* __restrict__ mem, const float* __restrict__ r,
    const float* __restrict__ Wq, const float* __restrict__ Wk, const float* __restrict__ Wv,
    const float* __restrict__ Wr, const float* __restrict__ Wo,
    unsigned short* __restrict__ catb, unsigned short* __restrict__ rb,
    unsigned short* __restrict__ wqt, unsigned short* __restrict__ wkvt,
    unsigned short* __restrict__ wrt,
    unsigned short* __restrict__ wohi, unsigned short* __restrict__ wolo)
{
  __shared__ unsigned short tH[64][72];
  __shared__ unsigned short tL[64][72];
  if (blockIdx.x < 6144) {
    int idx = blockIdx.x * 256 + threadIdx.x;           // 0 .. 1.5M-1
    if (idx < 1048576) {                                // catb: 4M u16, 4 per thread
      int e = idx * 4;
      int row = e >> 10, col = e & 1023;
      int b = row >> 11, t = row & 2047;
      const float* s = (t < 1024) ? &mem[((size_t)(b * 1024 + t)) * 1024 + col]
                                  : &h[((size_t)(b * 1024 + t - 1024)) * 1024 + col];
      float4 v = *(const float4*)s;
      *(ushort4*)&catb[e] = make_ushort4(f2bf(v.x), f2bf(v.y), f2bf(v.z), f2bf(v.w));
    } else {
      int e = (idx - 1048576) * 4;                      // rb: 2M elements
      float4 v = *(const float4*)&r[e];
      *(ushort4*)&rb[e] = make_ushort4(f2bf(v.x), f2bf(v.y), f2bf(v.z), f2bf(v.w));
    }
    return;
  }
  int q = blockIdx.x - 6144;
  int job = q >> 8;
  int tb = q & 255;
  int sr0 = (tb >> 4) * 64, sc0 = (tb & 15) * 64;
  const float* src = (job == 0) ? Wq : (job == 1) ? Wk : (job == 2) ? Wv : (job == 3) ? Wr : Wo;
  int tid = threadIdx.x;
  int rr = tid >> 4, c4 = (tid & 15) * 4;
#pragma unroll
  for (int i = 0; i < 4; ++i) {
    int row = rr + i * 16;
    float4 v = *(const float4*)&src[(size_t)(sr0 + row) * 1024 + sc0 + c4];
    float vv[4] = {v.x, v.y, v.z, v.w};
#pragma unroll
    for (int j = 0; j < 4; ++j) {
      unsigned short hi = f2bf(vv[j]);
      tH[c4 + j][row] = hi;
      if (job == 4) tL[c4 + j][row] = f2bf(vv[j] - bf2f(hi));
    }
  }
  __syncthreads();
  unsigned short* dst = (job == 0) ? wqt : (job == 1) ? wkvt
                      : (job == 2) ? (wkvt + (size_t)1024 * 1024)
                      : (job == 3) ? wrt : wohi;
#pragma unroll
  for (int i = 0; i < 4; ++i) {
    int row = rr + i * 16;
    size_t o = (size_t)(sc0 + row) * 1024 + sr0 + c4;
    *(ushort4*)&dst[o] = make_ushort4(tH[row][c4], tH[row][c4 + 1], tH[row][c4 + 2], tH[row][c4 + 3]);
    if (job == 4)
      *(ushort4*)&wolo[o] = make_ushort4(tL[row][c4], tL[row][c4 + 1], tL[row][c4 + 2], tL[row][c4 + 3]);
  }
}

// ---------------- projection GEMMs (bf16 MFMA, 128x128 tile, BK=32, double-buffered) --
// XCD-swizzled (768 = 8 x 96, bijective): each XCD owns a contiguous 96-block range so
// blocks sharing A/B panels hit the same L2.
__global__ __launch_bounds__(256) void gemm_all(
    const unsigned short* __restrict__ catb, const unsigned short* __restrict__ rb,
    const unsigned short* __restrict__ wqt, const unsigned short* __restrict__ wkvt,
    const unsigned short* __restrict__ wrt,
    const float* __restrict__ rwb, const float* __restrict__ rrb,
    unsigned short* __restrict__ qwP, unsigned short* __restrict__ qrP,
    unsigned short* __restrict__ kP, unsigned short* __restrict__ vP,
    unsigned short* __restrict__ rP)
{
  __shared__ __align__(16) unsigned short As[2][128 * 32];
  __shared__ __align__(16) unsigned short Bs[2][128 * 32];
  int blk = (blockIdx.x & 7) * 96 + (blockIdx.x >> 3);   // XCD swizzle (bijective on 768)
  int tid = threadIdx.x;
  int job, mb, nb;
  const unsigned short *A, *Bt;
  if (blk < 128)      { job = 0; A = catb; Bt = wqt;  mb = blk >> 3; nb = blk & 7; }
  else if (blk < 640) { job = 1; A = catb; Bt = wkvt; int q = blk - 128; mb = q >> 4; nb = q & 15; }
  else                { job = 2; A = rb;   Bt = wrt;  int q = blk - 640; mb = q >> 3; nb = q & 7; }

  const int w = tid >> 6;
  const int r0 = tid >> 2;                 // chunk0 row (0..63)
  const int c0u = (tid & 3) * 8;           // u16 col offset within 32-wide slab
  int ga_r0 = mb * 128 + r0, ga_r1 = mb * 128 + 64 + r0;
  if (job == 0) {
    ga_r0 = ((ga_r0 >> 10) << 11) + 1024 + (ga_r0 & 1023);
    ga_r1 = ((ga_r1 >> 10) << 11) + 1024 + (ga_r1 & 1023);
  }
  const unsigned short* gA0 = A + (size_t)ga_r0 * 1024 + c0u;
  const unsigned short* gA1 = A + (size_t)ga_r1 * 1024 + c0u;
  const unsigned short* gB0 = Bt + (size_t)(nb * 128 + r0) * 1024 + c0u;
  const unsigned short* gB1 = Bt + (size_t)(nb * 128 + 64 + r0) * 1024 + c0u;

  const int lane = tid & 63;
  const int lc = lane & 15, quad = lane >> 4;
  const int wm = (w & 1) * 64, wn = (w >> 1) * 64;

  auto stage = [&](int k0, int bi) {
    gl2lds16(gA0 + k0, (char*)As[bi] + w * 1024);
    gl2lds16(gA1 + k0, (char*)As[bi] + 4096 + w * 1024);
    gl2lds16(gB0 + k0, (char*)Bs[bi] + w * 1024);
    gl2lds16(gB1 + k0, (char*)Bs[bi] + 4096 + w * 1024);
  };

  f32x4 acc[4][4];
#pragma unroll
  for (int mt = 0; mt < 4; ++mt)
#pragma unroll
    for (int nt = 0; nt < 4; ++nt) { acc[mt][nt][0] = 0.f; acc[mt][nt][1] = 0.f; acc[mt][nt][2] = 0.f; acc[mt][nt][3] = 0.f; }

  stage(0, 0);
  __syncthreads();
  for (int k0 = 0; k0 < 1024; k0 += 32) {
    int cur = (k0 >> 5) & 1;
    if (k0 + 32 < 1024) stage(k0 + 32, cur ^ 1);
    s16x8 af[4], bfr[4];
#pragma unroll
    for (int mt = 0; mt < 4; ++mt) af[mt] = *(const s16x8*)&As[cur][(wm + mt * 16 + lc) * 32 + quad * 8];
#pragma unroll
    for (int nt = 0; nt < 4; ++nt) bfr[nt] = *(const s16x8*)&Bs[cur][(wn + nt * 16 + lc) * 32 + quad * 8];
#pragma unroll
    for (int mt = 0; mt < 4; ++mt)
#pragma unroll
      for (int nt = 0; nt < 4; ++nt) acc[mt][nt] = mfma16(af[mt], bfr[nt], acc[mt][nt]);
    __syncthreads();
  }

#pragma unroll
  for (int mt = 0; mt < 4; ++mt) {
    int t4 = mb * 128 + wm + mt * 16 + quad * 4;
#pragma unroll
    for (int nt = 0; nt < 4; ++nt) {
      int n = nb * 128 + wn + nt * 16 + lc;
      if (job == 0) {
        int hh = n >> 6, dh = n & 63;
        int f = dh >> 5, qd = (dh >> 3) & 3, j = dh & 7;
        float bw = rwb[n], br = rrb[n];
        int bb = t4 >> 10, trow = t4 & 1023;
        size_t tbb = ((((size_t)(bb * NH + hh) * 64 + (trow >> 4)) * 2 + f) * 512) + qd * 128 + j;
        int l0 = trow & 15;
#pragma unroll
        for (int rr = 0; rr < 4; ++rr) {
          qwP[tbb + (l0 + rr) * 8] = f2bf(acc[mt][nt][rr] + bw);
          qrP[tbb + (l0 + rr) * 8] = f2bf(acc[mt][nt][rr] + br);
        }
      } else if (job == 1) {
        int bb = t4 >> 11, t = t4 & 2047;
        if (n < 1024) {
          int hh = n >> 6, dh = n & 63;
          int f = dh >> 5, qd = (dh >> 3) & 3, j = dh & 7;
          size_t tbb = ((((size_t)(bb * NH + hh) * 128 + (t >> 4)) * 2 + f) * 512) + qd * 128 + j;
          int l0 = t & 15;
#pragma unroll
          for (int rr = 0; rr < 4; ++rr)
            kP[tbb + (l0 + rr) * 8] = f2bf(acc[mt][nt][rr]);
        } else {
          int n2 = n - 1024, hh = n2 >> 6, dh = n2 & 63;
          int bhv = bb * NH + hh;
          int kt = t >> 5;
          int ntv = dh >> 4;
          // key-permuted V A-frag: key tau=t&31 sits at lane-quad (tau>>2)&3, elem (tau&3)+4*((tau>>4)&1)
          int lanev = (((t >> 2) & 3) << 4) + (dh & 15);
          int elemv = ((t >> 4) & 1) << 2;          // t4 is a multiple of 4: elems elemv..elemv+3
          ushort4 pk = make_ushort4(f2bf(acc[mt][nt][0]), f2bf(acc[mt][nt][1]),
                                    f2bf(acc[mt][nt][2]), f2bf(acc[mt][nt][3]));
          *(ushort4*)&vP[(((size_t)bhv * 64 + kt) * 4 + ntv) * 512 + lanev * 8 + elemv] = pk;
        }
      } else {
        int hh = n >> 6, dh = n & 63;
        int f = dh >> 5, qd = (dh >> 3) & 3, j = dh & 7;
        size_t tbb = (((size_t)hh * 128 + (t4 >> 4)) * 2 + f) * 512 + qd * 128 + j;
        int l0 = t4 & 15;
#pragma unroll
        for (int rr = 0; rr < 4; ++rr)
          rP[tbb + (l0 + rr) * 8] = f2bf(acc[mt][nt][rr]);
      }
    }
  }
}

// ---------------- fused flash attention with rel-shift (bf16 MFMA) --------------------
// R8 configuration (best verified): bound(512,4), 66KB LDS, macro unroll-2 with named
// A/B register sets (no rotation movs, nothing pointer-passed -> no scratch).
// Phase 0 writes the BD strip PRE-SHIFTED; d==1025 diagonal zeroed at start.
// Main loop: swapped QK^T (mfma(K,Q)), BD folded into C operand, P lane-local via
// v_cvt_pk_bf16_f32 into key-permuted V tiles. XCD-swizzled grid.
#define BDSTR 2060          // u16 row stride: 1030 dwords = 6 mod 32 -> near-conflict-free b64 reads
#define OSTR 65             // f32 merge-row stride
__global__ __launch_bounds__(512, 4) void attn(
    const unsigned short* __restrict__ qwP, const unsigned short* __restrict__ qrP,
    const unsigned short* __restrict__ kP, const unsigned short* __restrict__ vP,
    const unsigned short* __restrict__ rP,
    unsigned short* __restrict__ avhi, unsigned short* __restrict__ avlo)
{
  __shared__ __align__(16) unsigned short bdS[16 * BDSTR];   // 65920 B
  float* oS = (float*)bdS;                 // merge overlay: [8][16][OSTR] f32
  float* lS = (float*)bdS + 8 * 16 * OSTR; // [8][16] f32

  const int tid = threadIdx.x;
  const int w = tid >> 6, lane = tid & 63;
  const int lc = lane & 15, quad = lane >> 4;
  // XCD swizzle: hw block -> semantic block so one (b,h)'s 64 q-tiles share an XCD L2
  const int sem = (blockIdx.x & 7) * 256 + (blockIdx.x >> 3);
  const int is = sem & 63, h = (sem >> 6) & 15, b = sem >> 10;
  const int i0 = is * 16;
  const size_t bh = (size_t)b * NH + h;

  const unsigned short* qwP_p = qwP + bh * 65536;
  const unsigned short* qrP_p = qrP + bh * 65536;
  const unsigned short* kP_p  = kP + bh * 131072;
  const unsigned short* vP_p  = vP + bh * (size_t)KL * DH + lane * 8;
  const unsigned short* rP_p  = rP + (size_t)h * 131072;

  // zero the d==1025 slots (key = q_glob+1025; no phase-0 writer targets them)
  if (tid < 16) {
    int kz = i0 + tid + 1025;
    if (kz < 2048) bdS[tid * BDSTR + kz] = 0;
  }

  // ---- phase 0: raw BD strip, stored pre-shifted. Wave w covers cols [w*256,w*256+256). ----
  {
    const int cmax = 1006 - i0;     // raw row i0+16 only needed at cols <= cmax
    s16x8 qa00 = *(const s16x8*)(qrP_p + is * 1024 + lane * 8);
    s16x8 qa01 = *(const s16x8*)(qrP_p + is * 1024 + 512 + lane * 8);
    int r1 = i0 + 16 + lc; if (r1 > 1023) r1 = 1023;   // clamp; clamped rows unused
    int off1 = (r1 >> 4) * 1024 + (quad * 16 + (r1 & 15)) * 8;
    s16x8 qa10 = *(const s16x8*)(qrP_p + off1);
    s16x8 qa11 = *(const s16x8*)(qrP_p + off1 + 512);
    const int xt0 = w * 16;
    const unsigned short* rp = rP_p + xt0 * 1024 + lane * 8;
    s16x8 rf0 = *(const s16x8*)rp;
    s16x8 rf1 = *(const s16x8*)(rp + 512);
    const int rbq = quad * 4 * BDSTR;        // per-lane row base (u16 units)
    for (int xt = xt0; xt < xt0 + 16; ++xt) {
      s16x8 cf0 = rf0, cf1 = rf1;
      if (xt + 1 < xt0 + 16) {
        const unsigned short* rpn = rP_p + (xt + 1) * 1024 + lane * 8;
        rf0 = *(const s16x8*)rpn;
        rf1 = *(const s16x8*)(rpn + 512);
      }
      f32x4 c0; c0[0] = 0.f; c0[1] = 0.f; c0[2] = 0.f; c0[3] = 0.f;
      c0 = mfma16(qa00, cf0, c0); c0 = mfma16(qa01, cf1, c0);
      int c = xt * 16 + lc;
#pragma unroll
      for (int rr = 0; rr < 4; ++rr) {
        int row = quad * 4 + rr;
        int s = c + i0 + row - 1023;               // direct key if >=0, else wrap to row-1
        int off = (s < 0) ? (s - 12) : s;          // (row-1)*BDSTR + (s+2048) == row*BDSTR + s - 12
        if (!(row == 0 && s < 0))
          bdS[rbq + rr * BDSTR + off] = f2bf(c0[rr]);
      }
      if (xt * 16 <= cmax) {                       // wave-uniform guard
        f32x4 c1; c1[0] = 0.f; c1[1] = 0.f; c1[2] = 0.f; c1[3] = 0.f;
        c1 = mfma16(qa10, cf0, c1); c1 = mfma16(qa11, cf1, c1);
        if (lane < 16) {                           // raw row i0+16 -> row 15, key = c+i0+1041
          int key2 = c + i0 + 1041;
          if (key2 < 2048) bdS[15 * BDSTR + key2] = f2bf(c1[0]);
        }
      }
    }
  }
  __syncthreads();

  // ---- main split-K loop: wave w handles k in [w*256, w*256+256), 8 x 32-key chunks ----
  s16x8 qwf0 = *(const s16x8*)(qwP_p + is * 1024 + lane * 8);
  s16x8 qwf1 = *(const s16x8*)(qwP_p + is * 1024 + 512 + lane * 8);

  f32x4 O[4];
#pragma unroll
  for (int nt = 0; nt < 4; ++nt) { O[nt][0] = 0.f; O[nt][1] = 0.f; O[nt][2] = 0.f; O[nt][3] = 0.f; }
  float lsumQ = 0.f;

  const unsigned short* bdlane = bdS + lc * BDSTR + quad * 4;   // q-row = lc, keys 4*quad+..
  const int base = w * 256;
  const float E2S = 0.18033688011112042f;    // 0.125 * log2(e)
  const float E2B = -17.312340490667562f;    // -12  * log2(e)

  // A/B named register sets; straight-line macros (no lambdas / pointer params).
  s16x8 ka0A, ka1A, kb0A, kb1A, v0A, v1A, v2A, v3A;
  s16x8 ka0B, ka1B, kb0B, kb1B, v0B, v1B, v2B, v3B;
  uint2 bq0A, bq1A, bq0B, bq1B;

#define LOADC(S, koff) { \
    const unsigned short* kp_ = kP_p + (size_t)((koff) >> 4) * 1024 + lane * 8; \
    ka0##S = *(const s16x8*)kp_; \
    ka1##S = *(const s16x8*)(kp_ + 512); \
    kb0##S = *(const s16x8*)(kp_ + 1024); \
    kb1##S = *(const s16x8*)(kp_ + 1536); \
    const unsigned short* bp_ = vP_p + (size_t)((koff) >> 5) * 2048; \
    v0##S = *(const s16x8*)bp_; \
    v1##S = *(const s16x8*)(bp_ + 512); \
    v2##S = *(const s16x8*)(bp_ + 1024); \
    v3##S = *(const s16x8*)(bp_ + 1536); \
    bq0##S = *(const uint2*)(bdlane + (koff)); \
    bq1##S = *(const uint2*)(bdlane + (koff) + 16); \
  }

#define COMPUTE(S) { \
    f32x4 c_; \
    c_[0] = __builtin_bit_cast(float, bq0##S.x << 16); \
    c_[1] = __builtin_bit_cast(float, bq0##S.x & 0xFFFF0000u); \
    c_[2] = __builtin_bit_cast(float, bq0##S.y << 16); \
    c_[3] = __builtin_bit_cast(float, bq0##S.y & 0xFFFF0000u); \
    c_ = mfma16(ka0##S, qwf0, c_); \
    c_ = mfma16(ka1##S, qwf1, c_); \
    f32x4 d_; \
    d_[0] = __builtin_bit_cast(float, bq1##S.x << 16); \
    d_[1] = __builtin_bit_cast(float, bq1##S.x & 0xFFFF0000u); \
    d_[2] = __builtin_bit_cast(float, bq1##S.y << 16); \
    d_[3] = __builtin_bit_cast(float, bq1##S.y & 0xFFFF0000u); \
    d_ = mfma16(kb0##S, qwf0, d_); \
    d_ = mfma16(kb1##S, qwf1, d_); \
    float p0_[4], p1_[4]; \
    _Pragma("unroll") \
    for (int rr_ = 0; rr_ < 4; ++rr_) { \
      p0_[rr_] = __builtin_amdgcn_exp2f(fmaf(c_[rr_], E2S, E2B)); \
      p1_[rr_] = __builtin_amdgcn_exp2f(fmaf(d_[rr_], E2S, E2B)); \
    } \
    lsumQ += ((p0_[0] + p0_[1]) + (p0_[2] + p0_[3])) + ((p1_[0] + p1_[1]) + (p1_[2] + p1_[3])); \
    unsigned int w0_, w1_, w2_, w3_; \
    asm("v_cvt_pk_bf16_f32 %0, %1, %2" : "=v"(w0_) : "v"(p0_[0]), "v"(p0_[1])); \
    asm("v_cvt_pk_bf16_f32 %0, %1, %2" : "=v"(w1_) : "v"(p0_[2]), "v"(p0_[3])); \
    asm("v_cvt_pk_bf16_f32 %0, %1, %2" : "=v"(w2_) : "v"(p1_[0]), "v"(p1_[1])); \
    asm("v_cvt_pk_bf16_f32 %0, %1, %2" : "=v"(w3_) : "v"(p1_[2]), "v"(p1_[3])); \
    u32x4 pw4_ = {w0_, w1_, w2_, w3_}; \
    s16x8 pf_ = __builtin_bit_cast(s16x8, pw4_); \
    O[0] = mfma16(v0##S, pf_, O[0]); \
    O[1] = mfma16(v1##S, pf_, O[1]); \
    O[2] = mfma16(v2##S, pf_, O[2]); \
    O[3] = mfma16(v3##S, pf_, O[3]); \
  }

  LOADC(A, base)
#pragma unroll 1
  for (int s = 0; s < 8; s += 2) {
    LOADC(B, base + (s + 1) * 32)       // chunk s+1 operands -> B while computing A
    COMPUTE(A)                          // chunk s
    if (s < 6) LOADC(A, base + (s + 2) * 32)   // chunk s+2 -> A while computing B
    COMPUTE(B)                          // chunk s+1
  }
#undef LOADC
#undef COMPUTE

  // row-sum over quads (q = lc is lane-local)
  lsumQ += __shfl_xor(lsumQ, 16);
  lsumQ += __shfl_xor(lsumQ, 32);

  // ---- merge: plain sums over 8 waves ----
  __syncthreads();               // all waves done with bdS reads
#pragma unroll
  for (int nt = 0; nt < 4; ++nt)
#pragma unroll
    for (int rr = 0; rr < 4; ++rr)
      oS[(w * 16 + lc) * OSTR + nt * 16 + quad * 4 + rr] = O[nt][rr];
  if (lane < 16) lS[w * 16 + lc] = lsumQ;
  __syncthreads();

  if (tid < 256) {
    int r = tid >> 4, c0 = (tid & 15) * 4;
    float L = 0.f, a0 = 0.f, a1 = 0.f, a2 = 0.f, a3 = 0.f;
#pragma unroll
    for (int wv = 0; wv < 8; ++wv) {
      L += lS[wv * 16 + r];
      const float* op = oS + (wv * 16 + r) * OSTR + c0;
      a0 += op[0]; a1 += op[1]; a2 += op[2]; a3 += op[3];
    }
    float inv = 1.0f / L;
    float v[4] = {a0 * inv, a1 * inv, a2 * inv, a3 * inv};
    unsigned short hi[4], lo[4];
#pragma unroll
    for (int j = 0; j < 4; ++j) {
      hi[j] = f2bf(v[j]);
      lo[j] = f2bf(v[j] - bf2f(hi[j]));
    }
    size_t oidx = ((size_t)(b * QL + i0 + r)) * DM + h * DH + c0;
    *(ushort4*)&avhi[oidx] = make_ushort4(hi[0], hi[1], hi[2], hi[3]);
    *(ushort4*)&avlo[oidx] = make_ushort4(lo[0], lo[1], lo[2], lo[3]);
  }
}

// ---------------- final GEMM: out = av @ Wo, fused 3-segment split-bf16 ----------------
// XCD-swizzled (512 = 8 x 64, bijective): each XCD owns 4 contiguous mb rows -> avhi/avlo
// panels stay L2-local; Wo panels (4 MB total) fit L2 regardless.
__global__ __launch_bounds__(256) void gemm_final(
    const unsigned short* __restrict__ avhi, const unsigned short* __restrict__ avlo,
    const unsigned short* __restrict__ wohi, const unsigned short* __restrict__ wolo,
    float* __restrict__ out)
{
  __shared__ __align__(16) unsigned short S[2][4][64 * 32];   // [buf][op][64][32]
  int tid = threadIdx.x;
  int sem = (blockIdx.x & 7) * 64 + (blockIdx.x >> 3);   // XCD swizzle
  int mb = sem >> 4, nb = sem & 15;    // 32 x 16

  const int w = tid >> 6, lane = tid & 63;
  const int srow = w * 16 + (lane >> 2);
  const int scu = (lane & 3) * 8;
  const size_t arow = (size_t)(mb * 64 + srow) * 1024 + scu;
  const size_t brow = (size_t)(nb * 64 + srow) * 1024 + scu;

  const int lc = lane & 15, quad = lane >> 4;
  const int wm = (w & 1) * 32, wn = (w >> 1) * 32;

  auto stage = [&](int k0, int bi) {
    gl2lds16(avhi + arow + k0, (char*)S[bi][0] + w * 1024);
    gl2lds16(avlo + arow + k0, (char*)S[bi][1] + w * 1024);
    gl2lds16(wohi + brow + k0, (char*)S[bi][2] + w * 1024);
    gl2lds16(wolo + brow + k0, (char*)S[bi][3] + w * 1024);
  };

  f32x4 acc[2][2];
#pragma unroll
  for (int mt = 0; mt < 2; ++mt)
#pragma unroll
    for (int nt = 0; nt < 2; ++nt) { acc[mt][nt][0] = 0.f; acc[mt][nt][1] = 0.f; acc[mt][nt][2] = 0.f; acc[mt][nt][3] = 0.f; }

  stage(0, 0);
  __syncthreads();
  for (int k0 = 0; k0 < 1024; k0 += 32) {
    int cur = (k0 >> 5) & 1;
    if (k0 + 32 < 1024) stage(k0 + 32, cur ^ 1);
    s16x8 ah[2], al[2], bh[2], bl[2];
#pragma unroll
    for (int mt = 0; mt < 2; ++mt) {
      int off = (wm + mt * 16 + lc) * 32 + quad * 8;
      ah[mt] = *(const s16x8*)&S[cur][0][off];
      al[mt] = *(const s16x8*)&S[cur][1][off];
    }
#pragma unroll
    for (int nt = 0; nt < 2; ++nt) {
      int off = (wn + nt * 16 + lc) * 32 + quad * 8;
      bh[nt] = *(const s16x8*)&S[cur][2][off];
      bl[nt] = *(const s16x8*)&S[cur][3][off];
    }
#pragma unroll
    for (int mt = 0; mt < 2; ++mt)
#pragma unroll
      for (int nt = 0; nt < 2; ++nt) {
        acc[mt][nt] = mfma16(ah[mt], bh[nt], acc[mt][nt]);
        acc[mt][nt] = mfma16(ah[mt], bl[nt], acc[mt][nt]);
        acc[mt][nt] = mfma16(al[mt], bh[nt], acc[mt][nt]);
      }
    __syncthreads();
  }

#pragma unroll
  for (int mt = 0; mt < 2; ++mt)
#pragma unroll
    for (int nt = 0; nt < 2; ++nt) {
      int n = nb * 64 + wn + nt * 16 + lc;
#pragma unroll
      for (int rr = 0; rr < 4; ++rr) {
        int m = mb * 64 + wm + mt * 16 + quad * 4 + rr;
        out[(size_t)m * 1024 + n] = acc[mt][nt][rr];
      }
    }
}

extern "C" void kernel_launch(void* const* d_in, const int* in_sizes, int n_in,
                              void* d_out, int out_size, void* d_ws, size_t ws_size,
                              hipStream_t stream) {
  (void)in_sizes; (void)n_in; (void)out_size; (void)ws_size;
  const float* h   = (const float*)d_in[0];
  const float* mem = (const float*)d_in[1];
  const float* r   = (const float*)d_in[2];
  const float* Wq  = (const float*)d_in[3];
  const float* Wk  = (const float*)d_in[4];
  const float* Wv  = (const float*)d_in[5];
  const float* Wr  = (const float*)d_in[6];
  const float* Wo  = (const float*)d_in[7];
  const float* rwb = (const float*)d_in[8];
  const float* rrb = (const float*)d_in[9];
  float* out = (float*)d_out;

  char* ws = (char*)d_ws;
  unsigned short* catb = (unsigned short*)(ws + 0);          // 8 MB
  unsigned short* rb   = (unsigned short*)(ws + 8388608);    // 4 MB
  unsigned short* wqt  = (unsigned short*)(ws + 12582912);   // 2 MB
  unsigned short* wkvt = (unsigned short*)(ws + 14680064);   // 4 MB
  unsigned short* wrt  = (unsigned short*)(ws + 18874368);   // 2 MB
  unsigned short* wohi = (unsigned short*)(ws + 20971520);   // 2 MB
  unsigned short* wolo = (unsigned short*)(ws + 23068672);   // 2 MB
  unsigned short* qwP  = (unsigned short*)(ws + 25165824);   // 4 MB (A-frag packed)
  unsigned short* qrP  = (unsigned short*)(ws + 29360128);   // 4 MB (A-frag packed)
  unsigned short* kPb  = (unsigned short*)(ws + 33554432);   // 8 MB (B-frag packed)
  unsigned short* vPb  = (unsigned short*)(ws + 41943040);   // 8 MB (key-permuted A-frag)
  unsigned short* rPb  = (unsigned short*)(ws + 50331648);   // 4 MB (B-frag packed)
  unsigned short* avhi = (unsigned short*)(ws + 54525952);   // 4 MB
  unsigned short* avlo = (unsigned short*)(ws + 58720256);   // 4 MB

  prep_all<<<7424, 256, 0, stream>>>(h, mem, r, Wq, Wk, Wv, Wr, Wo,
                                     catb, rb, wqt, wkvt, wrt, wohi, wolo);
  gemm_all<<<768, 256, 0, stream>>>(catb, rb, wqt, wkvt, wrt, rwb, rrb,
                                    qwP, qrP, kPb, vPb, rPb);
  attn<<<2048, 512, 0, stream>>>(qwP, qrP, kPb, vPb, rPb, avhi, avlo);
  gemm_final<<<512, 256, 0, stream>>>(avhi, avlo, wohi, wolo, out);
}

// Round 13
// 224.886 us; speedup vs baseline: 2.1144x; 1.0476x over previous
//
#include <hip/hip_runtime.h>

#define DM 1024
#define NH 16
#define DH 64
#define QL 1024
#define KL 2048

typedef short s16x8 __attribute__((ext_vector_type(8)));
typedef float f32x4 __attribute__((ext_vector_type(4)));
typedef unsigned int u32x4 __attribute__((ext_vector_type(4)));

__device__ __forceinline__ unsigned short f2bf(float f) {
  unsigned int u = __builtin_bit_cast(unsigned int, f);
  u += 0x7fffu + ((u >> 16) & 1u);
  return (unsigned short)(u >> 16);
}
__device__ __forceinline__ float bf2f(unsigned short b) {
  unsigned int u = ((unsigned int)b) << 16;
  return __builtin_bit_cast(float, u);
}
__device__ __forceinline__ f32x4 mfma16(s16x8 a, s16x8 b, f32x4 c) {
  return __builtin_amdgcn_mfma_f32_16x16x32_bf16(a, b, c, 0, 0, 0);
}
// async global->LDS, 16B per lane; LDS dest = wave-uniform base + lane*16
__device__ __forceinline__ void gl2lds16(const void* g, void* l) {
  __builtin_amdgcn_global_load_lds(
      (const __attribute__((address_space(1))) unsigned int*)g,
      (__attribute__((address_space(3))) unsigned int*)l, 16, 0, 0);
}

// Fragment-packed layouts (all bf16):
//  qP/qrP: [bh][qt=row/16][f=dim/32][lane=((dim>>3)&3)*16+(row&15)][j=dim&7]   (A-frag)
//  kP:     [bh][kt=key/16][f][lane][j]  (B-frag; lane=((dim>>3)&3)*16+(key&15))
//  rP:     [h][xt=row/16][f][lane][j]   (B-frag)
//  vP:     [bh][kt=key/32][nt=dim/16][lane=((key>>2)&3)*16+(dim&15)][e=(key&3)+4*((key>>4)&1)]
//          (A-frag of PV with keys PERMUTED inside each 32-tile by kappa(quad,e)=4q+(e&3)+16(e>>2),
//           so swapped-QK's lane-local P feeds PV's B operand with NO cross-lane movement.)
//
// Occupancy ledger (R9-R11): gfx950 rungs are total-regs<=64 -> 8 waves/SIMD,
// <=128 -> 4 waves/SIMD (unified VGPR+AGPR). attn body needs ~80 total -> pinned at
// 4 waves/SIMD regardless of LDS. bound(512,4) + 66KB LDS is the operating point.
// gemm_all XCD swizzle REVERTED (R12: +11us — grid fully co-resident, swizzle
// concentrated per-job working sets >4MB onto single XCD L2s).

// ---------------- fused prep: blocks 0..6143 input conversion, 6144..7423 weights ------
__global__ __launch_bounds__(256) void prep_all(
    const float* __restrict__ h, const float* __restrict__ mem, const float* __restrict__ r,
    const float* __restrict__ Wq, const float* __restrict__ Wk, const float* __restrict__ Wv,
    const float* __restrict__ Wr, const float* __restrict__ Wo,
    unsigned short* __restrict__ catb, unsigned short* __restrict__ rb,
    unsigned short* __restrict__ wqt, unsigned short* __restrict__ wkvt,
    unsigned short* __restrict__ wrt,
    unsigned short* __restrict__ wohi, unsigned short* __restrict__ wolo)
{
  __shared__ unsigned short tH[64][72];
  __shared__ unsigned short tL[64][72];
  if (blockIdx.x < 6144) {
    int idx = blockIdx.x * 256 + threadIdx.x;           // 0 .. 1.5M-1
    if (idx < 1048576) {                                // catb: 4M u16, 4 per thread
      int e = idx * 4;
      int row = e >> 10, col = e & 1023;
      int b = row >> 11, t = row & 2047;
      const float* s = (t < 1024) ? &mem[((size_t)(b * 1024 + t)) * 1024 + col]
                                  : &h[((size_t)(b * 1024 + t - 1024)) * 1024 + col];
      float4 v = *(const float4*)s;
      *(ushort4*)&catb[e] = make_ushort4(f2bf(v.x), f2bf(v.y), f2bf(v.z), f2bf(v.w));
    } else {
      int e = (idx - 1048576) * 4;                      // rb: 2M elements
      float4 v = *(const float4*)&r[e];
      *(ushort4*)&rb[e] = make_ushort4(f2bf(v.x), f2bf(v.y), f2bf(v.z), f2bf(v.w));
    }
    return;
  }
  int q = blockIdx.x - 6144;
  int job = q >> 8;
  int tb = q & 255;
  int sr0 = (tb >> 4) * 64, sc0 = (tb & 15) * 64;
  const float* src = (job == 0) ? Wq : (job == 1) ? Wk : (job == 2) ? Wv : (job == 3) ? Wr : Wo;
  int tid = threadIdx.x;
  int rr = tid >> 4, c4 = (tid & 15) * 4;
#pragma unroll
  for (int i = 0; i < 4; ++i) {
    int row = rr + i * 16;
    float4 v = *(const float4*)&src[(size_t)(sr0 + row) * 1024 + sc0 + c4];
    float vv[4] = {v.x, v.y, v.z, v.w};
#pragma unroll
    for (int j = 0; j < 4; ++j) {
      unsigned short hi = f2bf(vv[j]);
      tH[c4 + j][row] = hi;
      if (job == 4) tL[c4 + j][row] = f2bf(vv[j] - bf2f(hi));
    }
  }
  __syncthreads();
  unsigned short* dst = (job == 0) ? wqt : (job == 1) ? wkvt
                      : (job == 2) ? (wkvt + (size_t)1024 * 1024)
                      : (job == 3) ? wrt : wohi;
#pragma unroll
  for (int i = 0; i < 4; ++i) {
    int row = rr + i * 16;
    size_t o = (size_t)(sc0 + row) * 1024 + sr0 + c4;
    *(ushort4*)&dst[o] = make_ushort4(tH[row][c4], tH[row][c4 + 1], tH[row][c4 + 2], tH[row][c4 + 3]);
    if (job == 4)
      *(ushort4*)&wolo[o] = make_ushort4(tL[row][c4], tL[row][c4 + 1], tL[row][c4 + 2], tL[row][c4 + 3]);
  }
}

// ---------------- projection GEMMs (bf16 MFMA, 128x128 tile, BK=32, double-buffered) --
__global__ __launch_bounds__(256) void gemm_all(
    const unsigned short* __restrict__ catb, const unsigned short* __restrict__ rb,
    const unsigned short* __restrict__ wqt, const unsigned short* __restrict__ wkvt,
    const unsigned short* __restrict__ wrt,
    const float* __restrict__ rwb, const float* __restrict__ rrb,
    unsigned short* __restrict__ qwP, unsigned short* __restrict__ qrP,
    unsigned short* __restrict__ kP, unsigned short* __restrict__ vP,
    unsigned short* __restrict__ rP)
{
  __shared__ __align__(16) unsigned short As[2][128 * 32];
  __shared__ __align__(16) unsigned short Bs[2][128 * 32];
  int blk = blockIdx.x, tid = threadIdx.x;
  int job, mb, nb;
  const unsigned short *A, *Bt;
  if (blk < 128)      { job = 0; A = catb; Bt = wqt;  mb = blk >> 3; nb = blk & 7; }
  else if (blk < 640) { job = 1; A = catb; Bt = wkvt; int q = blk - 128; mb = q >> 4; nb = q & 15; }
  else                { job = 2; A = rb;   Bt = wrt;  int q = blk - 640; mb = q >> 3; nb = q & 7; }

  const int w = tid >> 6;
  const int r0 = tid >> 2;                 // chunk0 row (0..63)
  const int c0u = (tid & 3) * 8;           // u16 col offset within 32-wide slab
  int ga_r0 = mb * 128 + r0, ga_r1 = mb * 128 + 64 + r0;
  if (job == 0) {
    ga_r0 = ((ga_r0 >> 10) << 11) + 1024 + (ga_r0 & 1023);
    ga_r1 = ((ga_r1 >> 10) << 11) + 1024 + (ga_r1 & 1023);
  }
  const unsigned short* gA0 = A + (size_t)ga_r0 * 1024 + c0u;
  const unsigned short* gA1 = A + (size_t)ga_r1 * 1024 + c0u;
  const unsigned short* gB0 = Bt + (size_t)(nb * 128 + r0) * 1024 + c0u;
  const unsigned short* gB1 = Bt + (size_t)(nb * 128 + 64 + r0) * 1024 + c0u;

  const int lane = tid & 63;
  const int lc = lane & 15, quad = lane >> 4;
  const int wm = (w & 1) * 64, wn = (w >> 1) * 64;

  auto stage = [&](int k0, int bi) {
    gl2lds16(gA0 + k0, (char*)As[bi] + w * 1024);
    gl2lds16(gA1 + k0, (char*)As[bi] + 4096 + w * 1024);
    gl2lds16(gB0 + k0, (char*)Bs[bi] + w * 1024);
    gl2lds16(gB1 + k0, (char*)Bs[bi] + 4096 + w * 1024);
  };

  f32x4 acc[4][4];
#pragma unroll
  for (int mt = 0; mt < 4; ++mt)
#pragma unroll
    for (int nt = 0; nt < 4; ++nt) { acc[mt][nt][0] = 0.f; acc[mt][nt][1] = 0.f; acc[mt][nt][2] = 0.f; acc[mt][nt][3] = 0.f; }

  stage(0, 0);
  __syncthreads();
  for (int k0 = 0; k0 < 1024; k0 += 32) {
    int cur = (k0 >> 5) & 1;
    if (k0 + 32 < 1024) stage(k0 + 32, cur ^ 1);
    s16x8 af[4], bfr[4];
#pragma unroll
    for (int mt = 0; mt < 4; ++mt) af[mt] = *(const s16x8*)&As[cur][(wm + mt * 16 + lc) * 32 + quad * 8];
#pragma unroll
    for (int nt = 0; nt < 4; ++nt) bfr[nt] = *(const s16x8*)&Bs[cur][(wn + nt * 16 + lc) * 32 + quad * 8];
#pragma unroll
    for (int mt = 0; mt < 4; ++mt)
#pragma unroll
      for (int nt = 0; nt < 4; ++nt) acc[mt][nt] = mfma16(af[mt], bfr[nt], acc[mt][nt]);
    __syncthreads();
  }

#pragma unroll
  for (int mt = 0; mt < 4; ++mt) {
    int t4 = mb * 128 + wm + mt * 16 + quad * 4;
#pragma unroll
    for (int nt = 0; nt < 4; ++nt) {
      int n = nb * 128 + wn + nt * 16 + lc;
      if (job == 0) {
        int hh = n >> 6, dh = n & 63;
        int f = dh >> 5, qd = (dh >> 3) & 3, j = dh & 7;
        float bw = rwb[n], br = rrb[n];
        int bb = t4 >> 10, trow = t4 & 1023;
        size_t tbb = ((((size_t)(bb * NH + hh) * 64 + (trow >> 4)) * 2 + f) * 512) + qd * 128 + j;
        int l0 = trow & 15;
#pragma unroll
        for (int rr = 0; rr < 4; ++rr) {
          qwP[tbb + (l0 + rr) * 8] = f2bf(acc[mt][nt][rr] + bw);
          qrP[tbb + (l0 + rr) * 8] = f2bf(acc[mt][nt][rr] + br);
        }
      } else if (job == 1) {
        int bb = t4 >> 11, t = t4 & 2047;
        if (n < 1024) {
          int hh = n >> 6, dh = n & 63;
          int f = dh >> 5, qd = (dh >> 3) & 3, j = dh & 7;
          size_t tbb = ((((size_t)(bb * NH + hh) * 128 + (t >> 4)) * 2 + f) * 512) + qd * 128 + j;
          int l0 = t & 15;
#pragma unroll
          for (int rr = 0; rr < 4; ++rr)
            kP[tbb + (l0 + rr) * 8] = f2bf(acc[mt][nt][rr]);
        } else {
          int n2 = n - 1024, hh = n2 >> 6, dh = n2 & 63;
          int bhv = bb * NH + hh;
          int kt = t >> 5;
          int ntv = dh >> 4;
          // key-permuted V A-frag: key tau=t&31 sits at lane-quad (tau>>2)&3, elem (tau&3)+4*((tau>>4)&1)
          int lanev = (((t >> 2) & 3) << 4) + (dh & 15);
          int elemv = ((t >> 4) & 1) << 2;          // t4 is a multiple of 4: elems elemv..elemv+3
          ushort4 pk = make_ushort4(f2bf(acc[mt][nt][0]), f2bf(acc[mt][nt][1]),
                                    f2bf(acc[mt][nt][2]), f2bf(acc[mt][nt][3]));
          *(ushort4*)&vP[(((size_t)bhv * 64 + kt) * 4 + ntv) * 512 + lanev * 8 + elemv] = pk;
        }
      } else {
        int hh = n >> 6, dh = n & 63;
        int f = dh >> 5, qd = (dh >> 3) & 3, j = dh & 7;
        size_t tbb = (((size_t)hh * 128 + (t4 >> 4)) * 2 + f) * 512 + qd * 128 + j;
        int l0 = t4 & 15;
#pragma unroll
        for (int rr = 0; rr < 4; ++rr)
          rP[tbb + (l0 + rr) * 8] = f2bf(acc[mt][nt][rr]);
      }
    }
  }
}

// ---------------- fused flash attention with rel-shift (bf16 MFMA) --------------------
// Best verified config: bound(512,4), 66KB LDS, macro unroll-2 with named A/B register
// sets (no rotation movs, nothing pointer-passed -> no scratch).
// Phase 0 writes the BD strip PRE-SHIFTED; d==1025 diagonal zeroed at start.
// Main loop: swapped QK^T (mfma(K,Q)), BD folded into C operand, P lane-local via
// v_cvt_pk_bf16_f32 into key-permuted V tiles. XCD-swizzled grid.
#define BDSTR 2060          // u16 row stride: 1030 dwords = 6 mod 32 -> near-conflict-free b64 reads
#define OSTR 65             // f32 merge-row stride
__global__ __launch_bounds__(512, 4) void attn(
    const unsigned short* __restrict__ qwP, const unsigned short* __restrict__ qrP,
    const unsigned short* __restrict__ kP, const unsigned short* __restrict__ vP,
    const unsigned short* __restrict__ rP,
    unsigned short* __restrict__ avhi, unsigned short* __restrict__ avlo)
{
  __shared__ __align__(16) unsigned short bdS[16 * BDSTR];   // 65920 B
  float* oS = (float*)bdS;                 // merge overlay: [8][16][OSTR] f32
  float* lS = (float*)bdS + 8 * 16 * OSTR; // [8][16] f32

  const int tid = threadIdx.x;
  const int w = tid >> 6, lane = tid & 63;
  const int lc = lane & 15, quad = lane >> 4;
  // XCD swizzle: hw block -> semantic block so one (b,h)'s 64 q-tiles share an XCD L2
  const int sem = (blockIdx.x & 7) * 256 + (blockIdx.x >> 3);
  const int is = sem & 63, h = (sem >> 6) & 15, b = sem >> 10;
  const int i0 = is * 16;
  const size_t bh = (size_t)b * NH + h;

  const unsigned short* qwP_p = qwP + bh * 65536;
  const unsigned short* qrP_p = qrP + bh * 65536;
  const unsigned short* kP_p  = kP + bh * 131072;
  const unsigned short* vP_p  = vP + bh * (size_t)KL * DH + lane * 8;
  const unsigned short* rP_p  = rP + (size_t)h * 131072;

  // zero the d==1025 slots (key = q_glob+1025; no phase-0 writer targets them)
  if (tid < 16) {
    int kz = i0 + tid + 1025;
    if (kz < 2048) bdS[tid * BDSTR + kz] = 0;
  }

  // ---- phase 0: raw BD strip, stored pre-shifted. Wave w covers cols [w*256,w*256+256). ----
  {
    const int cmax = 1006 - i0;     // raw row i0+16 only needed at cols <= cmax
    s16x8 qa00 = *(const s16x8*)(qrP_p + is * 1024 + lane * 8);
    s16x8 qa01 = *(const s16x8*)(qrP_p + is * 1024 + 512 + lane * 8);
    int r1 = i0 + 16 + lc; if (r1 > 1023) r1 = 1023;   // clamp; clamped rows unused
    int off1 = (r1 >> 4) * 1024 + (quad * 16 + (r1 & 15)) * 8;
    s16x8 qa10 = *(const s16x8*)(qrP_p + off1);
    s16x8 qa11 = *(const s16x8*)(qrP_p + off1 + 512);
    const int xt0 = w * 16;
    const unsigned short* rp = rP_p + xt0 * 1024 + lane * 8;
    s16x8 rf0 = *(const s16x8*)rp;
    s16x8 rf1 = *(const s16x8*)(rp + 512);
    const int rbq = quad * 4 * BDSTR;        // per-lane row base (u16 units)
    for (int xt = xt0; xt < xt0 + 16; ++xt) {
      s16x8 cf0 = rf0, cf1 = rf1;
      if (xt + 1 < xt0 + 16) {
        const unsigned short* rpn = rP_p + (xt + 1) * 1024 + lane * 8;
        rf0 = *(const s16x8*)rpn;
        rf1 = *(const s16x8*)(rpn + 512);
      }
      f32x4 c0; c0[0] = 0.f; c0[1] = 0.f; c0[2] = 0.f; c0[3] = 0.f;
      c0 = mfma16(qa00, cf0, c0); c0 = mfma16(qa01, cf1, c0);
      int c = xt * 16 + lc;
#pragma unroll
      for (int rr = 0; rr < 4; ++rr) {
        int row = quad * 4 + rr;
        int s = c + i0 + row - 1023;               // direct key if >=0, else wrap to row-1
        int off = (s < 0) ? (s - 12) : s;          // (row-1)*BDSTR + (s+2048) == row*BDSTR + s - 12
        if (!(row == 0 && s < 0))
          bdS[rbq + rr * BDSTR + off] = f2bf(c0[rr]);
      }
      if (xt * 16 <= cmax) {                       // wave-uniform guard
        f32x4 c1; c1[0] = 0.f; c1[1] = 0.f; c1[2] = 0.f; c1[3] = 0.f;
        c1 = mfma16(qa10, cf0, c1); c1 = mfma16(qa11, cf1, c1);
        if (lane < 16) {                           // raw row i0+16 -> row 15, key = c+i0+1041
          int key2 = c + i0 + 1041;
          if (key2 < 2048) bdS[15 * BDSTR + key2] = f2bf(c1[0]);
        }
      }
    }
  }
  __syncthreads();

  // ---- main split-K loop: wave w handles k in [w*256, w*256+256), 8 x 32-key chunks ----
  s16x8 qwf0 = *(const s16x8*)(qwP_p + is * 1024 + lane * 8);
  s16x8 qwf1 = *(const s16x8*)(qwP_p + is * 1024 + 512 + lane * 8);

  f32x4 O[4];
#pragma unroll
  for (int nt = 0; nt < 4; ++nt) { O[nt][0] = 0.f; O[nt][1] = 0.f; O[nt][2] = 0.f; O[nt][3] = 0.f; }
  float lsumQ = 0.f;

  const unsigned short* bdlane = bdS + lc * BDSTR + quad * 4;   // q-row = lc, keys 4*quad+..
  const int base = w * 256;
  const float E2S = 0.18033688011112042f;    // 0.125 * log2(e)
  const float E2B = -17.312340490667562f;    // -12  * log2(e)

  // A/B named register sets; straight-line macros (no lambdas / pointer params).
  s16x8 ka0A, ka1A, kb0A, kb1A, v0A, v1A, v2A, v3A;
  s16x8 ka0B, ka1B, kb0B, kb1B, v0B, v1B, v2B, v3B;
  uint2 bq0A, bq1A, bq0B, bq1B;

#define LOADC(S, koff) { \
    const unsigned short* kp_ = kP_p + (size_t)((koff) >> 4) * 1024 + lane * 8; \
    ka0##S = *(const s16x8*)kp_; \
    ka1##S = *(const s16x8*)(kp_ + 512); \
    kb0##S = *(const s16x8*)(kp_ + 1024); \
    kb1##S = *(const s16x8*)(kp_ + 1536); \
    const unsigned short* bp_ = vP_p + (size_t)((koff) >> 5) * 2048; \
    v0##S = *(const s16x8*)bp_; \
    v1##S = *(const s16x8*)(bp_ + 512); \
    v2##S = *(const s16x8*)(bp_ + 1024); \
    v3##S = *(const s16x8*)(bp_ + 1536); \
    bq0##S = *(const uint2*)(bdlane + (koff)); \
    bq1##S = *(const uint2*)(bdlane + (koff) + 16); \
  }

#define COMPUTE(S) { \
    f32x4 c_; \
    c_[0] = __builtin_bit_cast(float, bq0##S.x << 16); \
    c_[1] = __builtin_bit_cast(float, bq0##S.x & 0xFFFF0000u); \
    c_[2] = __builtin_bit_cast(float, bq0##S.y << 16); \
    c_[3] = __builtin_bit_cast(float, bq0##S.y & 0xFFFF0000u); \
    c_ = mfma16(ka0##S, qwf0, c_); \
    c_ = mfma16(ka1##S, qwf1, c_); \
    f32x4 d_; \
    d_[0] = __builtin_bit_cast(float, bq1##S.x << 16); \
    d_[1] = __builtin_bit_cast(float, bq1##S.x & 0xFFFF0000u); \
    d_[2] = __builtin_bit_cast(float, bq1##S.y << 16); \
    d_[3] = __builtin_bit_cast(float, bq1##S.y & 0xFFFF0000u); \
    d_ = mfma16(kb0##S, qwf0, d_); \
    d_ = mfma16(kb1##S, qwf1, d_); \
    float p0_[4], p1_[4]; \
    _Pragma("unroll") \
    for (int rr_ = 0; rr_ < 4; ++rr_) { \
      p0_[rr_] = __builtin_amdgcn_exp2f(fmaf(c_[rr_], E2S, E2B)); \
      p1_[rr_] = __builtin_amdgcn_exp2f(fmaf(d_[rr_], E2S, E2B)); \
    } \
    lsumQ += ((p0_[0] + p0_[1]) + (p0_[2] + p0_[3])) + ((p1_[0] + p1_[1]) + (p1_[2] + p1_[3])); \
    unsigned int w0_, w1_, w2_, w3_; \
    asm("v_cvt_pk_bf16_f32 %0, %1, %2" : "=v"(w0_) : "v"(p0_[0]), "v"(p0_[1])); \
    asm("v_cvt_pk_bf16_f32 %0, %1, %2" : "=v"(w1_) : "v"(p0_[2]), "v"(p0_[3])); \
    asm("v_cvt_pk_bf16_f32 %0, %1, %2" : "=v"(w2_) : "v"(p1_[0]), "v"(p1_[1])); \
    asm("v_cvt_pk_bf16_f32 %0, %1, %2" : "=v"(w3_) : "v"(p1_[2]), "v"(p1_[3])); \
    u32x4 pw4_ = {w0_, w1_, w2_, w3_}; \
    s16x8 pf_ = __builtin_bit_cast(s16x8, pw4_); \
    O[0] = mfma16(v0##S, pf_, O[0]); \
    O[1] = mfma16(v1##S, pf_, O[1]); \
    O[2] = mfma16(v2##S, pf_, O[2]); \
    O[3] = mfma16(v3##S, pf_, O[3]); \
  }

  LOADC(A, base)
#pragma unroll 1
  for (int s = 0; s < 8; s += 2) {
    LOADC(B, base + (s + 1) * 32)       // chunk s+1 operands -> B while computing A
    COMPUTE(A)                          // chunk s
    if (s < 6) LOADC(A, base + (s + 2) * 32)   // chunk s+2 -> A while computing B
    COMPUTE(B)                          // chunk s+1
  }
#undef LOADC
#undef COMPUTE

  // row-sum over quads (q = lc is lane-local)
  lsumQ += __shfl_xor(lsumQ, 16);
  lsumQ += __shfl_xor(lsumQ, 32);

  // ---- merge: plain sums over 8 waves ----
  __syncthreads();               // all waves done with bdS reads
#pragma unroll
  for (int nt = 0; nt < 4; ++nt)
#pragma unroll
    for (int rr = 0; rr < 4; ++rr)
      oS[(w * 16 + lc) * OSTR + nt * 16 + quad * 4 + rr] = O[nt][rr];
  if (lane < 16) lS[w * 16 + lc] = lsumQ;
  __syncthreads();

  if (tid < 256) {
    int r = tid >> 4, c0 = (tid & 15) * 4;
    float L = 0.f, a0 = 0.f, a1 = 0.f, a2 = 0.f, a3 = 0.f;
#pragma unroll
    for (int wv = 0; wv < 8; ++wv) {
      L += lS[wv * 16 + r];
      const float* op = oS + (wv * 16 + r) * OSTR + c0;
      a0 += op[0]; a1 += op[1]; a2 += op[2]; a3 += op[3];
    }
    float inv = 1.0f / L;
    float v[4] = {a0 * inv, a1 * inv, a2 * inv, a3 * inv};
    unsigned short hi[4], lo[4];
#pragma unroll
    for (int j = 0; j < 4; ++j) {
      hi[j] = f2bf(v[j]);
      lo[j] = f2bf(v[j] - bf2f(hi[j]));
    }
    size_t oidx = ((size_t)(b * QL + i0 + r)) * DM + h * DH + c0;
    *(ushort4*)&avhi[oidx] = make_ushort4(hi[0], hi[1], hi[2], hi[3]);
    *(ushort4*)&avlo[oidx] = make_ushort4(lo[0], lo[1], lo[2], lo[3]);
  }
}

// ---------------- final GEMM: out = av @ Wo, fused 3-segment split-bf16 ----------------
// XCD-swizzled (512 = 8 x 64, bijective): each XCD owns 4 contiguous mb rows -> avhi/avlo
// panels stay L2-local; Wo panels (4 MB total) fit L2 regardless.
__global__ __launch_bounds__(256) void gemm_final(
    const unsigned short* __restrict__ avhi, const unsigned short* __restrict__ avlo,
    const unsigned short* __restrict__ wohi, const unsigned short* __restrict__ wolo,
    float* __restrict__ out)
{
  __shared__ __align__(16) unsigned short S[2][4][64 * 32];   // [buf][op][64][32]
  int tid = threadIdx.x;
  int sem = (blockIdx.x & 7) * 64 + (blockIdx.x >> 3);   // XCD swizzle
  int mb = sem >> 4, nb = sem & 15;    // 32 x 16

  const int w = tid >> 6, lane = tid & 63;
  const int srow = w * 16 + (lane >> 2);
  const int scu = (lane & 3) * 8;
  const size_t arow = (size_t)(mb * 64 + srow) * 1024 + scu;
  const size_t brow = (size_t)(nb * 64 + srow) * 1024 + scu;

  const int lc = lane & 15, quad = lane >> 4;
  const int wm = (w & 1) * 32, wn = (w >> 1) * 32;

  auto stage = [&](int k0, int bi) {
    gl2lds16(avhi + arow + k0, (char*)S[bi][0] + w * 1024);
    gl2lds16(avlo + arow + k0, (char*)S[bi][1] + w * 1024);
    gl2lds16(wohi + brow + k0, (char*)S[bi][2] + w * 1024);
    gl2lds16(wolo + brow + k0, (char*)S[bi][3] + w * 1024);
  };

  f32x4 acc[2][2];
#pragma unroll
  for (int mt = 0; mt < 2; ++mt)
#pragma unroll
    for (int nt = 0; nt < 2; ++nt) { acc[mt][nt][0] = 0.f; acc[mt][nt][1] = 0.f; acc[mt][nt][2] = 0.f; acc[mt][nt][3] = 0.f; }

  stage(0, 0);
  __syncthreads();
  for (int k0 = 0; k0 < 1024; k0 += 32) {
    int cur = (k0 >> 5) & 1;
    if (k0 + 32 < 1024) stage(k0 + 32, cur ^ 1);
    s16x8 ah[2], al[2], bh[2], bl[2];
#pragma unroll
    for (int mt = 0; mt < 2; ++mt) {
      int off = (wm + mt * 16 + lc) * 32 + quad * 8;
      ah[mt] = *(const s16x8*)&S[cur][0][off];
      al[mt] = *(const s16x8*)&S[cur][1][off];
    }
#pragma unroll
    for (int nt = 0; nt < 2; ++nt) {
      int off = (wn + nt * 16 + lc) * 32 + quad * 8;
      bh[nt] = *(const s16x8*)&S[cur][2][off];
      bl[nt] = *(const s16x8*)&S[cur][3][off];
    }
#pragma unroll
    for (int mt = 0; mt < 2; ++mt)
#pragma unroll
      for (int nt = 0; nt < 2; ++nt) {
        acc[mt][nt] = mfma16(ah[mt], bh[nt], acc[mt][nt]);
        acc[mt][nt] = mfma16(ah[mt], bl[nt], acc[mt][nt]);
        acc[mt][nt] = mfma16(al[mt], bh[nt], acc[mt][nt]);
      }
    __syncthreads();
  }

#pragma unroll
  for (int mt = 0; mt < 2; ++mt)
#pragma unroll
    for (int nt = 0; nt < 2; ++nt) {
      int n = nb * 64 + wn + nt * 16 + lc;
#pragma unroll
      for (int rr = 0; rr < 4; ++rr) {
        int m = mb * 64 + wm + mt * 16 + quad * 4 + rr;
        out[(size_t)m * 1024 + n] = acc[mt][nt][rr];
      }
    }
}

extern "C" void kernel_launch(void* const* d_in, const int* in_sizes, int n_in,
                              void* d_out, int out_size, void* d_ws, size_t ws_size,
                              hipStream_t stream) {
  (void)in_sizes; (void)n_in; (void)out_size; (void)ws_size;
  const float* h   = (const float*)d_in[0];
  const float* mem = (const float*)d_in[1];
  const float* r   = (const float*)d_in[2];
  const float* Wq  = (const float*)d_in[3];
  const float* Wk  = (const float*)d_in[4];
  const float* Wv  = (const float*)d_in[5];
  const float* Wr  = (const float*)d_in[6];
  const float* Wo  = (const float*)d_in[7];
  const float* rwb = (const float*)d_in[8];
  const float* rrb = (const float*)d_in[9];
  float* out = (float*)d_out;

  char* ws = (char*)d_ws;
  unsigned short* catb = (unsigned short*)(ws + 0);          // 8 MB
  unsigned short* rb   = (unsigned short*)(ws + 8388608);    // 4 MB
  unsigned short* wqt  = (unsigned short*)(ws + 12582912);   // 2 MB
  unsigned short* wkvt = (unsigned short*)(ws + 14680064);   // 4 MB
  unsigned short* wrt  = (unsigned short*)(ws + 18874368);   // 2 MB
  unsigned short* wohi = (unsigned short*)(ws + 20971520);   // 2 MB
  unsigned short* wolo = (unsigned short*)(ws + 23068672);   // 2 MB
  unsigned short* qwP  = (unsigned short*)(ws + 25165824);   // 4 MB (A-frag packed)
  unsigned short* qrP  = (unsigned short*)(ws + 29360128);   // 4 MB (A-frag packed)
  unsigned short* kPb  = (unsigned short*)(ws + 33554432);   // 8 MB (B-frag packed)
  unsigned short* vPb  = (unsigned short*)(ws + 41943040);   // 8 MB (key-permuted A-frag)
  unsigned short* rPb  = (unsigned short*)(ws + 50331648);   // 4 MB (B-frag packed)
  unsigned short* avhi = (unsigned short*)(ws + 54525952);   // 4 MB
  unsigned short* avlo = (unsigned short*)(ws + 58720256);   // 4 MB

  prep_all<<<7424, 256, 0, stream>>>(h, mem, r, Wq, Wk, Wv, Wr, Wo,
                                     catb, rb, wqt, wkvt, wrt, wohi, wolo);
  gemm_all<<<768, 256, 0, stream>>>(catb, rb, wqt, wkvt, wrt, rwb, rrb,
                                    qwP, qrP, kPb, vPb, rPb);
  attn<<<2048, 512, 0, stream>>>(qwP, qrP, kPb, vPb, rPb, avhi, avlo);
  gemm_final<<<512, 256, 0, stream>>>(avhi, avlo, wohi, wolo, out);
}